// Round 20
// baseline (357.209 us; speedup 1.0000x reference)
//
#include <hip/hip_runtime.h>
#include <math.h>

#define H 128
#define W 128
#define NB 8
#define NFC 64

typedef __attribute__((ext_vector_type(8))) short s16x8;
typedef __attribute__((ext_vector_type(4))) short s16x4;
typedef __attribute__((ext_vector_type(4))) float f32x4;
typedef __attribute__((ext_vector_type(4))) int   i32x4;
typedef __attribute__((ext_vector_type(2))) int   i32x2;

__device__ __forceinline__ float b2f(short s) {
    return __uint_as_float(((unsigned)(unsigned short)s) << 16);
}
__device__ __forceinline__ short f2bf(float f) {
    unsigned u = __float_as_uint(f);
    u += 0x7FFF + ((u >> 16) & 1);
    return (short)(u >> 16);
}
__device__ __forceinline__ short f2h(float f) {
    _Float16 h = (_Float16)f;
    return __builtin_bit_cast(short, h);
}
__device__ __forceinline__ float h2f(short s) {
    return (float)__builtin_bit_cast(_Float16, s);
}

// ---------------------------------------------------------------------------
// all weight transforms in one launch -> wpool bf16 [768][9][64]
// ---------------------------------------------------------------------------
__global__ __launch_bounds__(256) void k_wt_all(
    const float* __restrict__ w1, const float* __restrict__ w2,
    const float* __restrict__ w3, const float* __restrict__ w4,
    const float* __restrict__ dcw, short* __restrict__ wp)
{
    int idx = blockIdx.x * 256 + threadIdx.x;   // < 442368
    int u = idx / 576;
    int r = idx - u * 576;
    int t = r >> 6, i = r & 63;
    float v;
    if (u < 128) {
        int o = u & 63, icoff = (u >> 6) << 6;
        v = w1[((size_t)(o * 128) + icoff + i) * 9 + t];
    } else if (u < 192) {
        int o = u - 128;
        v = w2[((size_t)(o * 64) + i) * 9 + t];
    } else if (u < 256) {
        int o = u - 192;
        v = w3[((size_t)(o * 64) + i) * 9 + t];
    } else if (u < 704) {
        int o = u - 256;
        v = (o < 432) ? w4[((size_t)(o * 64) + i) * 9 + t] : 0.f;
    } else {
        int o = u - 704;
        v = dcw[((size_t)(o * 64) + i) * 9 + t];
    }
    wp[idx] = f2bf(v);
}

// ---------------------------------------------------------------------------
// NCHW fp32 -> (nbr: g-planar bf16 [n][16][128][128][4]) and (ref: NHWC bf16)
// ---------------------------------------------------------------------------
__global__ __launch_bounds__(256) void k_nhwc2(const float* __restrict__ nbr,
                                               const float* __restrict__ ref,
                                               short* __restrict__ nbrG,
                                               short* __restrict__ refH)
{
    int px = blockIdx.x * 256 + threadIdx.x;
    bool isNbr = (px < 131072);
    const float* src;
    if (isNbr) { src = nbr; }
    else       { src = ref; px -= 131072; }
    int n = px >> 14;
    int sp = px & 16383;
    const float* s = src + (size_t)n * 64 * 16384 + sp;
    unsigned pk[32];
    #pragma unroll
    for (int c = 0; c < 32; ++c) {
        float v0 = s[(size_t)(2 * c) * 16384];
        float v1 = s[(size_t)(2 * c + 1) * 16384];
        pk[c] = (unsigned)(unsigned short)f2bf(v0) |
                ((unsigned)(unsigned short)f2bf(v1) << 16);
    }
    if (isNbr) {
        #pragma unroll
        for (int g = 0; g < 16; ++g) {
            i32x2 t;
            t[0] = pk[2 * g]; t[1] = pk[2 * g + 1];
            *(i32x2*)(nbrG + ((size_t)(n * 16 + g) * 16384 + sp) * 4) = t;
        }
    } else {
        i32x4* d = (i32x4*)(refH + (size_t)(n * 16384 + sp) * 64);
        #pragma unroll
        for (int qq = 0; qq < 8; ++qq) {
            i32x4 t;
            t[0] = pk[4 * qq]; t[1] = pk[4 * qq + 1];
            t[2] = pk[4 * qq + 2]; t[3] = pk[4 * qq + 3];
            d[qq] = t;
        }
    }
}

// ---------------------------------------------------------------------------
// backwarp: nbrG (g-planar bf16) + flow -> warped (NHWC bf16)
// ---------------------------------------------------------------------------
__global__ __launch_bounds__(256) void k_backwarp(const short* __restrict__ nbrG,
                                                  const float* __restrict__ flow,
                                                  short* __restrict__ warped)
{
    int idx = blockIdx.x * 256 + threadIdx.x;
    int px = idx >> 2, qt = idx & 3;
    int n = px >> 14;
    int x = px & 127, y = (px >> 7) & 127;
    float fx = flow[(size_t)(n * 2 + 0) * 16384 + y * 128 + x];
    float fy = flow[(size_t)(n * 2 + 1) * 16384 + y * 128 + x];
    float pxf = (float)x + fx, pyf = (float)y + fy;
    float x0f = floorf(pxf), y0f = floorf(pyf);
    int x0 = (int)x0f, y0 = (int)y0f;
    float dx = pxf - x0f, dy = pyf - y0f;
    float vy0 = ((unsigned)y0 < 128u) ? 1.f : 0.f;
    float vy1 = ((unsigned)(y0 + 1) < 128u) ? 1.f : 0.f;
    float vx0 = ((unsigned)x0 < 128u) ? 1.f : 0.f;
    float vx1 = ((unsigned)(x0 + 1) < 128u) ? 1.f : 0.f;
    float w00 = (1.f - dy) * (1.f - dx) * vy0 * vx0;
    float w01 = (1.f - dy) * dx * vy0 * vx1;
    float w10 = dy * (1.f - dx) * vy1 * vx0;
    float w11 = dy * dx * vy1 * vx1;
    int y0c = min(max(y0, 0), 127), y1c = min(max(y0 + 1, 0), 127);
    int x0c = min(max(x0, 0), 127), x1c = min(max(x0 + 1, 0), 127);
    int xb = min(max(x0, 0), 126);
    bool s0 = (x0c == xb), s1 = (x1c == xb);

    const short* plbase = nbrG + (size_t)n * 16 * 65536;
    s16x8 r0, r1;
    #pragma unroll
    for (int pg = 0; pg < 4; ++pg) {
        const short* pl = plbase + (size_t)(qt * 4 + pg) * 65536;
        s16x8 p0 = *(const s16x8*)(pl + (y0c * 128 + xb) * 4);
        s16x8 p1 = *(const s16x8*)(pl + (y1c * 128 + xb) * 4);
        #pragma unroll
        for (int cc = 0; cc < 4; ++cc) {
            float v00 = b2f(s0 ? p0[cc] : p0[4 + cc]);
            float v01 = b2f(s1 ? p0[cc] : p0[4 + cc]);
            float v10 = b2f(s0 ? p1[cc] : p1[4 + cc]);
            float v11 = b2f(s1 ? p1[cc] : p1[4 + cc]);
            float v = w00 * v00 + w01 * v01 + w10 * v10 + w11 * v11;
            short res = f2bf(v);
            if (pg < 2) r0[pg * 4 + cc] = res;
            else        r1[(pg - 2) * 4 + cc] = res;
        }
    }
    short* o = warped + (size_t)px * 64 + qt * 16;
    *(s16x8*)o = r0;
    *(s16x8*)(o + 8) = r1;
}

// ---------------------------------------------------------------------------
// MFMA conv3x3, IC=64. 512 threads / 8 waves; block = 16x16 px tile.
// Wave = 64oc x 2 patches, dbuf aS, 1 barrier/tap.
// TAP LOOP FULLY UNROLLED: all LDS addresses become base+immediate.
// MODE 3 epilogue: tap/g-grouped offset+mask planes (round-14).
// ---------------------------------------------------------------------------
template<int MODE>
__global__ __launch_bounds__(512) void k_conv(
    const short* __restrict__ in, const short* __restrict__ wT,
    const float* __restrict__ bias,
    float* __restrict__ partial, short* __restrict__ outB,
    int* __restrict__ offP, short* __restrict__ maskP,
    const float* __restrict__ flow, int n0)
{
    __shared__ __align__(16) short tileS[324 * 64];   // 18x18 halo x 64ch
    __shared__ __align__(16) short aS[2][64 * 64];

    int tid = threadIdx.x;
    int bid = blockIdx.x;
    int og = (MODE == 3) ? blockIdx.y : 0;
    int n  = (MODE == 3) ? (n0 + (bid >> 6)) : (bid >> 6);
    int tl = bid & 63;
    int bx = (tl & 7) << 4;
    int by = (tl >> 3) << 4;
    int ln = tid & 63, wv = tid >> 6;      // wv 0..7
    int c = ln & 15, q = ln >> 4;

    for (int i = tid; i < 2592; i += 512) {
        int pt = i >> 3, c16 = i & 7;
        int ty = pt / 18, tx = pt - ty * 18;
        int gy = by + ty - 1, gx = bx + tx - 1;
        i32x4 v = {0, 0, 0, 0};
        if ((unsigned)gy < 128u && (unsigned)gx < 128u)
            v = *(const i32x4*)(in + (((size_t)n * 128 + gy) * 128 + gx) * 64 + c16 * 8);
        *(i32x4*)((char*)tileS + pt * 128 + ((c16 ^ (pt & 7)) << 4)) = v;
    }

    const short* wbase = wT + ((MODE == 3) ? (size_t)og * 36864 : 0);
    int aoc = tid >> 3, ac8 = tid & 7;     // 64 rows x 8 chunks = 512 threads
    {
        i32x4 t0 = *(const i32x4*)(wbase + (size_t)aoc * 576 + ac8 * 8);
        *(i32x4*)((char*)aS[0] + aoc * 128 + ((ac8 ^ (aoc & 7)) << 4)) = t0;
    }
    i32x4 sa = *(const i32x4*)(wbase + (size_t)aoc * 576 + 64 + ac8 * 8);

    f32x4 acc[4][2];
    #pragma unroll
    for (int m = 0; m < 4; ++m) {
        acc[m][0] = (f32x4){0.f, 0.f, 0.f, 0.f};
        acc[m][1] = (f32x4){0.f, 0.f, 0.f, 0.f};
    }

    int p0 = 2 * wv, p1 = 2 * wv + 1;      // patches 0..15 in 4x4 grid
    int pby0 = (p0 >> 2) << 2, pbx0 = (p0 & 3) << 2;
    int pby1 = (p1 >> 2) << 2, pbx1 = (p1 & 3) << 2;
    int cy = c >> 2, cx = c & 3;
    int base0 = (pby0 + cy) * 18 + pbx0 + cx;   // tap-invariant patch bases
    int base1 = (pby1 + cy) * 18 + pbx1 + cx;

    __syncthreads();  // tile + aS[0] ready

    #pragma unroll
    for (int tap = 0; tap < 9; ++tap) {
        int cur = tap & 1;
        if (tap < 8) {
            *(i32x4*)((char*)aS[cur ^ 1] + aoc * 128 + ((ac8 ^ (aoc & 7)) << 4)) = sa;
            if (tap < 7)
                sa = *(const i32x4*)(wbase + (size_t)aoc * 576 + (tap + 2) * 64 + ac8 * 8);
        }

        int dty = tap / 3, dtx = tap - dty * 3;   // compile-time after unroll
        int pta = base0 + dty * 18 + dtx;
        int ptb = base1 + dty * 18 + dtx;
        #pragma unroll
        for (int ih = 0; ih < 2; ++ih) {
            int slot = ih * 4 + q;
            s16x8 bf0 = *(const s16x8*)((const char*)tileS + pta * 128 + ((slot ^ (pta & 7)) << 4));
            s16x8 bf1 = *(const s16x8*)((const char*)tileS + ptb * 128 + ((slot ^ (ptb & 7)) << 4));
            #pragma unroll
            for (int m = 0; m < 4; ++m) {
                int ocl = m * 16 + c;
                s16x8 a = *(const s16x8*)((const char*)aS[cur] + ocl * 128 + ((slot ^ (ocl & 7)) << 4));
                acc[m][0] = __builtin_amdgcn_mfma_f32_16x16x32_bf16(a, bf0, acc[m][0], 0, 0, 0);
                acc[m][1] = __builtin_amdgcn_mfma_f32_16x16x32_bf16(a, bf1, acc[m][1], 0, 0, 0);
            }
        }
        if (tap < 8) __syncthreads();  // aS[cur^1] written; reads of aS[cur] done
    }

    #pragma unroll
    for (int p = 0; p < 2; ++p) {
        int pby = p ? pby1 : pby0;
        int pbx = p ? pbx1 : pbx0;
        int y = by + pby + cy;
        int x = bx + pbx + cx;
        size_t pxi = ((size_t)n * 128 + y) * 128 + x;
        float fy = 0.f, fx2 = 0.f;
        if (MODE == 3) {
            fy  = flow[(size_t)(n * 2 + 1) * 16384 + y * 128 + x];
            fx2 = flow[(size_t)(n * 2 + 0) * 16384 + y * 128 + x];
        }
        #pragma unroll
        for (int m = 0; m < 4; ++m) {
            int o0 = m * 16 + q * 4;
            f32x4 v = acc[m][p];
            if (MODE == 0) {
                *(f32x4*)(partial + pxi * 64 + o0) = v;
            } else if (MODE == 1 || MODE == 2) {
                f32x4 bv = *(const f32x4*)(bias + o0);
                if (MODE == 1) {
                    f32x4 pv = *(const f32x4*)(partial + pxi * 64 + o0);
                    v += pv;
                }
                v += bv;
                s16x4 r;
                #pragma unroll
                for (int j = 0; j < 4; ++j) {
                    float t = v[j];
                    t = t >= 0.f ? t : 0.1f * t;
                    r[j] = f2bf(t);
                }
                *(s16x4*)(outB + pxi * 64 + o0) = r;
            } else {  // MODE 3: tap/g-grouped offset+mask planes
                int oc4 = og * 64 + o0;
                if (oc4 < 432) {
                    f32x4 bv = *(const f32x4*)(bias + oc4);
                    v += bv;
                    size_t nrel = (size_t)(bid >> 6);
                    int pxl = y * 128 + x;
                    if (oc4 < 288) {
                        int gk0 = oc4 >> 1;
                        int g0 = gk0 / 9, t0 = gk0 - g0 * 9;
                        int gk1 = gk0 + 1;
                        int g1 = gk1 / 9, t1 = gk1 - g1 * 9;
                        unsigned pk0 = (unsigned)(unsigned short)f2h(v[0] + fy) |
                                       ((unsigned)(unsigned short)f2h(v[1] + fx2) << 16);
                        unsigned pk1 = (unsigned)(unsigned short)f2h(v[2] + fy) |
                                       ((unsigned)(unsigned short)f2h(v[3] + fx2) << 16);
                        offP[(((nrel * 9 + t0) * 4 + (g0 >> 2)) * 16384 + (size_t)pxl) * 4 + (g0 & 3)] = (int)pk0;
                        offP[(((nrel * 9 + t1) * 4 + (g1 >> 2)) * 16384 + (size_t)pxl) * 4 + (g1 & 3)] = (int)pk1;
                    } else {
                        int gkb = oc4 - 288;
                        #pragma unroll
                        for (int j = 0; j < 4; ++j) {
                            int gk = gkb + j;
                            int g = gk / 9, t = gk - g * 9;
                            maskP[(((nrel * 9 + t) * 4 + (g >> 2)) * 16384 + (size_t)pxl) * 4 + (g & 3)] =
                                f2h(1.f / (1.f + expf(-v[j])));
                        }
                    }
                }
            }
        }
    }
}

// ---------------------------------------------------------------------------
// DCN: block = 64-pixel row strip, 4 waves (round-14-proven, unchanged).
// ---------------------------------------------------------------------------
__global__ __launch_bounds__(256) void k_dcn(
    const int* __restrict__ offP, const short* __restrict__ maskP,
    const short* __restrict__ nbrG, const short* __restrict__ dcwT,
    const float* __restrict__ dcb, float* __restrict__ out, int n0)
{
    __shared__ __align__(16) short smp[64 * 64];  // [px][ic], 16B-chunk XOR swizzle
    __shared__ __align__(16) short aS[64 * 64];

    int tid = threadIdx.x;
    int bid = blockIdx.x;            // 4 img * 256 strips
    int nrel = bid >> 8;
    int rb = bid & 255;
    int y = rb >> 1;
    int xh = (rb & 1) << 6;
    int n = n0 + nrel;

    int xt = tid & 63;               // x within strip (sample phase)
    int sg = tid >> 6;               // wave id = g-group
    int ln = tid & 63, c = ln & 15, q = ln >> 4;
    int x = xh + xt;
    int pxl = y * 128 + x;

    int aoc = tid >> 3, ac8 = tid & 7;
    i32x4 sa0 = *(const i32x4*)(dcwT + (size_t)aoc * 576 + ac8 * 8);
    i32x4 sa1 = *(const i32x4*)(dcwT + (size_t)(aoc + 32) * 576 + ac8 * 8);

    const short* plg0 = nbrG + (size_t)(n * 16 + sg * 4) * 65536;

    f32x4 acc[4];
    #pragma unroll
    for (int m = 0; m < 4; ++m) acc[m] = (f32x4){0.f, 0.f, 0.f, 0.f};

    int brow = sg * 16 + c;          // wave's output pixel row in smp

    for (int tap = 0; tap < 9; ++tap) {
        int dty = tap / 3 - 1, dtx = tap - (tap / 3) * 3 - 1;
        size_t obase = (((size_t)(nrel * 9 + tap) * 4 + sg) * 16384 + pxl) * 4;
        i32x4 dd4 = *(const i32x4*)(offP + obase);
        s16x4 mk4 = *(const s16x4*)(maskP + obase);

        s16x8 r01[2];
        #pragma unroll
        for (int gg = 0; gg < 4; ++gg) {
            float dyv = h2f((short)(dd4[gg] & 0xffff));
            float dxv = h2f((short)(((unsigned)dd4[gg]) >> 16));
            float mk  = h2f(mk4[gg]);
            float sy = (float)(y + dty) + dyv;
            float sx = (float)(x + dtx) + dxv;
            float y0f = floorf(sy), x0f = floorf(sx);
            int y0 = (int)y0f, x0 = (int)x0f;
            float ddy = sy - y0f, ddx = sx - x0f;
            float vy0 = ((unsigned)y0 < 128u) ? 1.f : 0.f;
            float vy1 = ((unsigned)(y0 + 1) < 128u) ? 1.f : 0.f;
            float vx0 = ((unsigned)x0 < 128u) ? 1.f : 0.f;
            float vx1 = ((unsigned)(x0 + 1) < 128u) ? 1.f : 0.f;
            float w00 = (1.f - ddy) * (1.f - ddx) * vy0 * vx0;
            float w01 = (1.f - ddy) * ddx * vy0 * vx1;
            float w10 = ddy * (1.f - ddx) * vy1 * vx0;
            float w11 = ddy * ddx * vy1 * vx1;
            int y0c = min(max(y0, 0), 127), y1c = min(max(y0 + 1, 0), 127);
            int x0c = min(max(x0, 0), 127), x1c = min(max(x0 + 1, 0), 127);
            int xb = min(max(x0, 0), 126);
            bool sel0 = (x0c == xb), sel1 = (x1c == xb);
            const short* plg = plg0 + (size_t)gg * 65536;
            s16x8 pr0 = *(const s16x8*)(plg + (y0c * 128 + xb) * 4);
            s16x8 pr1 = *(const s16x8*)(plg + (y1c * 128 + xb) * 4);
            #pragma unroll
            for (int cc = 0; cc < 4; ++cc) {
                float v00 = b2f(sel0 ? pr0[cc] : pr0[4 + cc]);
                float v01 = b2f(sel1 ? pr0[cc] : pr0[4 + cc]);
                float v10 = b2f(sel0 ? pr1[cc] : pr1[4 + cc]);
                float v11 = b2f(sel1 ? pr1[cc] : pr1[4 + cc]);
                float sv = w00 * v00 + w01 * v01 + w10 * v10 + w11 * v11;
                r01[gg >> 1][(gg & 1) * 4 + cc] = f2bf(sv * mk);
            }
        }
        // write samples: row xt, chunks sg*2, sg*2+1 (XOR swizzle)
        *(s16x8*)((char*)smp + xt * 128 + (((sg * 2 + 0) ^ (xt & 7)) << 4)) = r01[0];
        *(s16x8*)((char*)smp + xt * 128 + (((sg * 2 + 1) ^ (xt & 7)) << 4)) = r01[1];
        // stage A (conv-proven pattern) + prefetch next tap
        *(i32x4*)((char*)aS + aoc * 128 + ((ac8 ^ (aoc & 7)) << 4)) = sa0;
        *(i32x4*)((char*)aS + (aoc + 32) * 128 + ((ac8 ^ ((aoc + 32) & 7)) << 4)) = sa1;
        if (tap < 8) {
            sa0 = *(const i32x4*)(dcwT + (size_t)aoc * 576 + (tap + 1) * 64 + ac8 * 8);
            sa1 = *(const i32x4*)(dcwT + (size_t)(aoc + 32) * 576 + (tap + 1) * 64 + ac8 * 8);
        }
        __syncthreads();  // smp + aS ready

        #pragma unroll
        for (int ih = 0; ih < 2; ++ih) {
            int slot = ih * 4 + q;
            s16x8 bf = *(const s16x8*)((const char*)smp + brow * 128 + ((slot ^ (brow & 7)) << 4));
            #pragma unroll
            for (int m = 0; m < 4; ++m) {
                int ocl = m * 16 + c;
                s16x8 a = *(const s16x8*)((const char*)aS + ocl * 128 + ((slot ^ (ocl & 7)) << 4));
                acc[m] = __builtin_amdgcn_mfma_f32_16x16x32_bf16(a, bf, acc[m], 0, 0, 0);
            }
        }
        __syncthreads();  // done reading smp/aS
    }

    #pragma unroll
    for (int m = 0; m < 4; ++m) {
        int o0 = m * 16 + q * 4;
        f32x4 bv = *(const f32x4*)(dcb + o0);
        f32x4 v = acc[m] + bv;
        int xo = xh + sg * 16 + c;
        #pragma unroll
        for (int j = 0; j < 4; ++j) {
            float t = v[j];
            t = t >= 0.f ? t : 0.1f * t;
            out[((size_t)n * 64 + o0 + j) * 16384 + y * 128 + xo] = t;
        }
    }
}

// ---------------------------------------------------------------------------
extern "C" void kernel_launch(void* const* d_in, const int* in_sizes, int n_in,
                              void* d_out, int out_size, void* d_ws, size_t ws_size,
                              hipStream_t stream)
{
    const float* nbr  = (const float*)d_in[0];
    const float* ref  = (const float*)d_in[1];
    const float* flow = (const float*)d_in[2];
    const float* w1   = (const float*)d_in[3];
    const float* b1   = (const float*)d_in[4];
    const float* w2   = (const float*)d_in[5];
    const float* b2   = (const float*)d_in[6];
    const float* w3   = (const float*)d_in[7];
    const float* b3   = (const float*)d_in[8];
    const float* w4   = (const float*)d_in[9];
    const float* b4   = (const float*)d_in[10];
    const float* dcw  = (const float*)d_in[11];
    const float* dcb  = (const float*)d_in[12];
    float* out = (float*)d_out;
    char* ws = (char*)d_ws;

    // ws layout (bytes), peak 91.23 MB (proven rounds 6/8/13/14/18/19).
    short* nbrG   = (short*)ws;
    short* wpool  = (short*)(ws + 16777216);
    short* warped = (short*)(ws + 17825792);
    short* refH   = (short*)(ws + 34603008);
    float* h1p    = (float*)(ws + 51380224);
    int*   offP   = (int*)(ws + 17825792);
    short* maskP  = (short*)(ws + 55574528);
    short* h3     = (short*)(ws + 74448896);
    short* h1     = warped;
    short* h2     = refH;

    short* wT1a = wpool;            // w1 ic 0-63
    short* wT1b = wpool + 36864;    // w1 ic 64-127
    short* wT2  = wpool + 73728;
    short* wT3  = wpool + 110592;
    short* wT4  = wpool + 147456;   // [448][9][64]
    short* dcwT = wpool + 405504;

    k_wt_all<<<1728, 256, 0, stream>>>(w1, w2, w3, w4, dcw, wpool);
    k_nhwc2<<<1024, 256, 0, stream>>>(nbr, ref, nbrG, refH);
    k_backwarp<<<2048, 256, 0, stream>>>(nbrG, flow, warped);

    // conv1 as two IC-64 passes (16x16 tiles, 512-thread blocks)
    k_conv<0><<<512, 512, 0, stream>>>(warped, wT1a, nullptr, h1p, nullptr, nullptr, nullptr, nullptr, 0);
    k_conv<1><<<512, 512, 0, stream>>>(refH, wT1b, b1, h1p, h1, nullptr, nullptr, nullptr, 0);
    k_conv<2><<<512, 512, 0, stream>>>(h1, wT2, b2, nullptr, h2, nullptr, nullptr, nullptr, 0);
    k_conv<2><<<512, 512, 0, stream>>>(h2, wT3, b3, nullptr, h3, nullptr, nullptr, nullptr, 0);

    // conv4 + DCN in 4-image chunks
    for (int n0 = 0; n0 < 8; n0 += 4) {
        dim3 g4(256, 7);
        k_conv<3><<<g4, 512, 0, stream>>>(h3, wT4, b4, nullptr, nullptr, offP, maskP, flow, n0);
        k_dcn<<<1024, 256, 0, stream>>>(offP, maskP, nbrG, dcwT, dcb, out, n0);
    }
}

// Round 21
// 333.279 us; speedup vs baseline: 1.0718x; 1.0718x over previous
//
#include <hip/hip_runtime.h>
#include <math.h>

#define H 128
#define W 128
#define NB 8
#define NFC 64

typedef __attribute__((ext_vector_type(8))) short s16x8;
typedef __attribute__((ext_vector_type(4))) short s16x4;
typedef __attribute__((ext_vector_type(4))) float f32x4;
typedef __attribute__((ext_vector_type(4))) int   i32x4;
typedef __attribute__((ext_vector_type(2))) int   i32x2;

__device__ __forceinline__ float b2f(short s) {
    return __uint_as_float(((unsigned)(unsigned short)s) << 16);
}
__device__ __forceinline__ short f2bf(float f) {
    unsigned u = __float_as_uint(f);
    u += 0x7FFF + ((u >> 16) & 1);
    return (short)(u >> 16);
}
__device__ __forceinline__ short f2h(float f) {
    _Float16 h = (_Float16)f;
    return __builtin_bit_cast(short, h);
}
__device__ __forceinline__ float h2f(short s) {
    return (float)__builtin_bit_cast(_Float16, s);
}

// ---------------------------------------------------------------------------
// all weight transforms in one launch -> wpool bf16 [768][9][64]
// ---------------------------------------------------------------------------
__global__ __launch_bounds__(256) void k_wt_all(
    const float* __restrict__ w1, const float* __restrict__ w2,
    const float* __restrict__ w3, const float* __restrict__ w4,
    const float* __restrict__ dcw, short* __restrict__ wp)
{
    int idx = blockIdx.x * 256 + threadIdx.x;   // < 442368
    int u = idx / 576;
    int r = idx - u * 576;
    int t = r >> 6, i = r & 63;
    float v;
    if (u < 128) {
        int o = u & 63, icoff = (u >> 6) << 6;
        v = w1[((size_t)(o * 128) + icoff + i) * 9 + t];
    } else if (u < 192) {
        int o = u - 128;
        v = w2[((size_t)(o * 64) + i) * 9 + t];
    } else if (u < 256) {
        int o = u - 192;
        v = w3[((size_t)(o * 64) + i) * 9 + t];
    } else if (u < 704) {
        int o = u - 256;
        v = (o < 432) ? w4[((size_t)(o * 64) + i) * 9 + t] : 0.f;
    } else {
        int o = u - 704;
        v = dcw[((size_t)(o * 64) + i) * 9 + t];
    }
    wp[idx] = f2bf(v);
}

// ---------------------------------------------------------------------------
// NCHW fp32 -> (nbr: g-planar bf16 [n][16][128][128][4]) and (ref: NHWC bf16)
// ---------------------------------------------------------------------------
__global__ __launch_bounds__(256) void k_nhwc2(const float* __restrict__ nbr,
                                               const float* __restrict__ ref,
                                               short* __restrict__ nbrG,
                                               short* __restrict__ refH)
{
    int px = blockIdx.x * 256 + threadIdx.x;
    bool isNbr = (px < 131072);
    const float* src;
    if (isNbr) { src = nbr; }
    else       { src = ref; px -= 131072; }
    int n = px >> 14;
    int sp = px & 16383;
    const float* s = src + (size_t)n * 64 * 16384 + sp;
    unsigned pk[32];
    #pragma unroll
    for (int c = 0; c < 32; ++c) {
        float v0 = s[(size_t)(2 * c) * 16384];
        float v1 = s[(size_t)(2 * c + 1) * 16384];
        pk[c] = (unsigned)(unsigned short)f2bf(v0) |
                ((unsigned)(unsigned short)f2bf(v1) << 16);
    }
    if (isNbr) {
        #pragma unroll
        for (int g = 0; g < 16; ++g) {
            i32x2 t;
            t[0] = pk[2 * g]; t[1] = pk[2 * g + 1];
            *(i32x2*)(nbrG + ((size_t)(n * 16 + g) * 16384 + sp) * 4) = t;
        }
    } else {
        i32x4* d = (i32x4*)(refH + (size_t)(n * 16384 + sp) * 64);
        #pragma unroll
        for (int qq = 0; qq < 8; ++qq) {
            i32x4 t;
            t[0] = pk[4 * qq]; t[1] = pk[4 * qq + 1];
            t[2] = pk[4 * qq + 2]; t[3] = pk[4 * qq + 3];
            d[qq] = t;
        }
    }
}

// ---------------------------------------------------------------------------
// backwarp: nbrG (g-planar bf16) + flow -> warped (NHWC bf16)
// ---------------------------------------------------------------------------
__global__ __launch_bounds__(256) void k_backwarp(const short* __restrict__ nbrG,
                                                  const float* __restrict__ flow,
                                                  short* __restrict__ warped)
{
    int idx = blockIdx.x * 256 + threadIdx.x;
    int px = idx >> 2, qt = idx & 3;
    int n = px >> 14;
    int x = px & 127, y = (px >> 7) & 127;
    float fx = flow[(size_t)(n * 2 + 0) * 16384 + y * 128 + x];
    float fy = flow[(size_t)(n * 2 + 1) * 16384 + y * 128 + x];
    float pxf = (float)x + fx, pyf = (float)y + fy;
    float x0f = floorf(pxf), y0f = floorf(pyf);
    int x0 = (int)x0f, y0 = (int)y0f;
    float dx = pxf - x0f, dy = pyf - y0f;
    float vy0 = ((unsigned)y0 < 128u) ? 1.f : 0.f;
    float vy1 = ((unsigned)(y0 + 1) < 128u) ? 1.f : 0.f;
    float vx0 = ((unsigned)x0 < 128u) ? 1.f : 0.f;
    float vx1 = ((unsigned)(x0 + 1) < 128u) ? 1.f : 0.f;
    float w00 = (1.f - dy) * (1.f - dx) * vy0 * vx0;
    float w01 = (1.f - dy) * dx * vy0 * vx1;
    float w10 = dy * (1.f - dx) * vy1 * vx0;
    float w11 = dy * dx * vy1 * vx1;
    int y0c = min(max(y0, 0), 127), y1c = min(max(y0 + 1, 0), 127);
    int x0c = min(max(x0, 0), 127), x1c = min(max(x0 + 1, 0), 127);
    int xb = min(max(x0, 0), 126);
    bool s0 = (x0c == xb), s1 = (x1c == xb);

    const short* plbase = nbrG + (size_t)n * 16 * 65536;
    s16x8 r0, r1;
    #pragma unroll
    for (int pg = 0; pg < 4; ++pg) {
        const short* pl = plbase + (size_t)(qt * 4 + pg) * 65536;
        s16x8 p0 = *(const s16x8*)(pl + (y0c * 128 + xb) * 4);
        s16x8 p1 = *(const s16x8*)(pl + (y1c * 128 + xb) * 4);
        #pragma unroll
        for (int cc = 0; cc < 4; ++cc) {
            float v00 = b2f(s0 ? p0[cc] : p0[4 + cc]);
            float v01 = b2f(s1 ? p0[cc] : p0[4 + cc]);
            float v10 = b2f(s0 ? p1[cc] : p1[4 + cc]);
            float v11 = b2f(s1 ? p1[cc] : p1[4 + cc]);
            float v = w00 * v00 + w01 * v01 + w10 * v10 + w11 * v11;
            short res = f2bf(v);
            if (pg < 2) r0[pg * 4 + cc] = res;
            else        r1[(pg - 2) * 4 + cc] = res;
        }
    }
    short* o = warped + (size_t)px * 64 + qt * 16;
    *(s16x8*)o = r0;
    *(s16x8*)(o + 8) = r1;
}

// ---------------------------------------------------------------------------
// MFMA conv3x3, IC=64 (round-18-proven: dbuf aS, 1 barrier/tap).
// MODE 3 epilogue writes G-PLANAR offset+mask planes:
//   offP  int32 [nrel][tap][g:16][px:16384]   (dy lo16, dx hi16)
//   maskP fp16  [nrel][tap][g:16][px:16384]
// -> 64B-run coalesced writes (16 x-adjacent lanes share (tap,g)).
// ---------------------------------------------------------------------------
template<int MODE>
__global__ __launch_bounds__(256) void k_conv(
    const short* __restrict__ in, const short* __restrict__ wT,
    const float* __restrict__ bias,
    float* __restrict__ partial, short* __restrict__ outB,
    int* __restrict__ offP, short* __restrict__ maskP,
    const float* __restrict__ flow, int n0)
{
    __shared__ __align__(16) short tileS[180 * 64];
    __shared__ __align__(16) short aS[2][64 * 64];

    int tid = threadIdx.x;
    int bid = blockIdx.x;
    int og = (MODE == 3) ? blockIdx.y : 0;
    int n  = (MODE == 3) ? (n0 + (bid >> 7)) : (bid >> 7);
    int tl = bid & 127;
    int bx = (tl & 7) << 4;
    int by = (tl >> 3) << 3;
    int ln = tid & 63, wv = tid >> 6;
    int c = ln & 15, q = ln >> 4;

    for (int i = tid; i < 1440; i += 256) {
        int pt = i >> 3, c16 = i & 7;
        int ty = pt / 18, tx = pt - ty * 18;
        int gy = by + ty - 1, gx = bx + tx - 1;
        i32x4 v = {0, 0, 0, 0};
        if ((unsigned)gy < 128u && (unsigned)gx < 128u)
            v = *(const i32x4*)(in + (((size_t)n * 128 + gy) * 128 + gx) * 64 + c16 * 8);
        *(i32x4*)((char*)tileS + pt * 128 + ((c16 ^ (pt & 7)) << 4)) = v;
    }

    const short* wbase = wT + ((MODE == 3) ? (size_t)og * 36864 : 0);
    int aoc = tid >> 3, ac8 = tid & 7;
    {
        i32x4 t0a = *(const i32x4*)(wbase + (size_t)aoc * 576 + ac8 * 8);
        i32x4 t0b = *(const i32x4*)(wbase + (size_t)(aoc + 32) * 576 + ac8 * 8);
        *(i32x4*)((char*)aS[0] + aoc * 128 + ((ac8 ^ (aoc & 7)) << 4)) = t0a;
        *(i32x4*)((char*)aS[0] + (aoc + 32) * 128 + ((ac8 ^ ((aoc + 32) & 7)) << 4)) = t0b;
    }
    i32x4 sa0 = *(const i32x4*)(wbase + (size_t)aoc * 576 + 64 + ac8 * 8);
    i32x4 sa1 = *(const i32x4*)(wbase + (size_t)(aoc + 32) * 576 + 64 + ac8 * 8);

    f32x4 acc[4][2];
    #pragma unroll
    for (int m = 0; m < 4; ++m) {
        acc[m][0] = (f32x4){0.f, 0.f, 0.f, 0.f};
        acc[m][1] = (f32x4){0.f, 0.f, 0.f, 0.f};
    }

    int p0 = 2 * wv, p1 = 2 * wv + 1;
    int pby0 = (p0 >> 2) << 2, pbx0 = (p0 & 3) << 2;
    int pby1 = (p1 >> 2) << 2, pbx1 = (p1 & 3) << 2;
    int cy = c >> 2, cx = c & 3;

    __syncthreads();  // tile + aS[0] ready

    for (int tap = 0; tap < 9; ++tap) {
        int cur = tap & 1;
        if (tap < 8) {
            *(i32x4*)((char*)aS[cur ^ 1] + aoc * 128 + ((ac8 ^ (aoc & 7)) << 4)) = sa0;
            *(i32x4*)((char*)aS[cur ^ 1] + (aoc + 32) * 128 + ((ac8 ^ ((aoc + 32) & 7)) << 4)) = sa1;
            if (tap < 7) {
                sa0 = *(const i32x4*)(wbase + (size_t)aoc * 576 + (tap + 2) * 64 + ac8 * 8);
                sa1 = *(const i32x4*)(wbase + (size_t)(aoc + 32) * 576 + (tap + 2) * 64 + ac8 * 8);
            }
        }

        int dty = tap / 3, dtx = tap - dty * 3;
        int pta = (pby0 + cy + dty) * 18 + pbx0 + cx + dtx;
        int ptb = (pby1 + cy + dty) * 18 + pbx1 + cx + dtx;
        #pragma unroll
        for (int ih = 0; ih < 2; ++ih) {
            int slot = ih * 4 + q;
            s16x8 bf0 = *(const s16x8*)((const char*)tileS + pta * 128 + ((slot ^ (pta & 7)) << 4));
            s16x8 bf1 = *(const s16x8*)((const char*)tileS + ptb * 128 + ((slot ^ (ptb & 7)) << 4));
            #pragma unroll
            for (int m = 0; m < 4; ++m) {
                int ocl = m * 16 + c;
                s16x8 a = *(const s16x8*)((const char*)aS[cur] + ocl * 128 + ((slot ^ (ocl & 7)) << 4));
                acc[m][0] = __builtin_amdgcn_mfma_f32_16x16x32_bf16(a, bf0, acc[m][0], 0, 0, 0);
                acc[m][1] = __builtin_amdgcn_mfma_f32_16x16x32_bf16(a, bf1, acc[m][1], 0, 0, 0);
            }
        }
        if (tap < 8) __syncthreads();
    }

    #pragma unroll
    for (int p = 0; p < 2; ++p) {
        int pby = p ? pby1 : pby0;
        int pbx = p ? pbx1 : pbx0;
        int y = by + pby + cy;
        int x = bx + pbx + cx;
        size_t pxi = ((size_t)n * 128 + y) * 128 + x;
        float fy = 0.f, fx2 = 0.f;
        if (MODE == 3) {
            fy  = flow[(size_t)(n * 2 + 1) * 16384 + y * 128 + x];
            fx2 = flow[(size_t)(n * 2 + 0) * 16384 + y * 128 + x];
        }
        #pragma unroll
        for (int m = 0; m < 4; ++m) {
            int o0 = m * 16 + q * 4;
            f32x4 v = acc[m][p];
            if (MODE == 0) {
                *(f32x4*)(partial + pxi * 64 + o0) = v;
            } else if (MODE == 1 || MODE == 2) {
                f32x4 bv = *(const f32x4*)(bias + o0);
                if (MODE == 1) {
                    f32x4 pv = *(const f32x4*)(partial + pxi * 64 + o0);
                    v += pv;
                }
                v += bv;
                s16x4 r;
                #pragma unroll
                for (int j = 0; j < 4; ++j) {
                    float t = v[j];
                    t = t >= 0.f ? t : 0.1f * t;
                    r[j] = f2bf(t);
                }
                *(s16x4*)(outB + pxi * 64 + o0) = r;
            } else {  // MODE 3: g-planar offset+mask planes
                int oc4 = og * 64 + o0;
                if (oc4 < 432) {
                    f32x4 bv = *(const f32x4*)(bias + oc4);
                    v += bv;
                    size_t nrel = (size_t)(bid >> 7);
                    int pxl = y * 128 + x;
                    if (oc4 < 288) {
                        int gk0 = oc4 >> 1;
                        int g0 = gk0 / 9, t0 = gk0 - g0 * 9;
                        int gk1 = gk0 + 1;
                        int g1 = gk1 / 9, t1 = gk1 - g1 * 9;
                        unsigned pk0 = (unsigned)(unsigned short)f2h(v[0] + fy) |
                                       ((unsigned)(unsigned short)f2h(v[1] + fx2) << 16);
                        unsigned pk1 = (unsigned)(unsigned short)f2h(v[2] + fy) |
                                       ((unsigned)(unsigned short)f2h(v[3] + fx2) << 16);
                        offP[((nrel * 9 + t0) * 16 + g0) * 16384 + (size_t)pxl] = (int)pk0;
                        offP[((nrel * 9 + t1) * 16 + g1) * 16384 + (size_t)pxl] = (int)pk1;
                    } else {
                        int gkb = oc4 - 288;
                        #pragma unroll
                        for (int j = 0; j < 4; ++j) {
                            int gk = gkb + j;
                            int g = gk / 9, t = gk - g * 9;
                            maskP[((nrel * 9 + t) * 16 + g) * 16384 + (size_t)pxl] =
                                f2h(1.f / (1.f + expf(-v[j])));
                        }
                    }
                }
            }
        }
    }
}

// ---------------------------------------------------------------------------
// DCN: block = 64-pixel row strip, 4 waves (round-14-proven). G-planar
// offP/maskP: per tap, 4x dense 4B off loads + 4x dense 2B mask loads.
// ---------------------------------------------------------------------------
__global__ __launch_bounds__(256) void k_dcn(
    const int* __restrict__ offP, const short* __restrict__ maskP,
    const short* __restrict__ nbrG, const short* __restrict__ dcwT,
    const float* __restrict__ dcb, float* __restrict__ out, int n0)
{
    __shared__ __align__(16) short smp[64 * 64];  // [px][ic], 16B-chunk XOR swizzle
    __shared__ __align__(16) short aS[64 * 64];

    int tid = threadIdx.x;
    int bid = blockIdx.x;            // 4 img * 256 strips
    int nrel = bid >> 8;
    int rb = bid & 255;
    int y = rb >> 1;
    int xh = (rb & 1) << 6;
    int n = n0 + nrel;

    int xt = tid & 63;               // x within strip (sample phase)
    int sg = tid >> 6;               // wave id = g-group
    int ln = tid & 63, c = ln & 15, q = ln >> 4;
    int x = xh + xt;
    int pxl = y * 128 + x;

    int aoc = tid >> 3, ac8 = tid & 7;
    i32x4 sa0 = *(const i32x4*)(dcwT + (size_t)aoc * 576 + ac8 * 8);
    i32x4 sa1 = *(const i32x4*)(dcwT + (size_t)(aoc + 32) * 576 + ac8 * 8);

    const short* plg0 = nbrG + (size_t)(n * 16 + sg * 4) * 65536;

    f32x4 acc[4];
    #pragma unroll
    for (int m = 0; m < 4; ++m) acc[m] = (f32x4){0.f, 0.f, 0.f, 0.f};

    int brow = sg * 16 + c;          // wave's output pixel row in smp

    for (int tap = 0; tap < 9; ++tap) {
        int dty = tap / 3 - 1, dtx = tap - (tap / 3) * 3 - 1;
        size_t pbase = ((size_t)(nrel * 9 + tap) * 16 + sg * 4) * 16384 + pxl;
        i32x4 dd4;
        s16x4 mk4;
        #pragma unroll
        for (int gg = 0; gg < 4; ++gg) {
            dd4[gg] = offP[pbase + (size_t)gg * 16384];
            mk4[gg] = maskP[pbase + (size_t)gg * 16384];
        }

        s16x8 r01[2];
        #pragma unroll
        for (int gg = 0; gg < 4; ++gg) {
            float dyv = h2f((short)(dd4[gg] & 0xffff));
            float dxv = h2f((short)(((unsigned)dd4[gg]) >> 16));
            float mk  = h2f(mk4[gg]);
            float sy = (float)(y + dty) + dyv;
            float sx = (float)(x + dtx) + dxv;
            float y0f = floorf(sy), x0f = floorf(sx);
            int y0 = (int)y0f, x0 = (int)x0f;
            float ddy = sy - y0f, ddx = sx - x0f;
            float vy0 = ((unsigned)y0 < 128u) ? 1.f : 0.f;
            float vy1 = ((unsigned)(y0 + 1) < 128u) ? 1.f : 0.f;
            float vx0 = ((unsigned)x0 < 128u) ? 1.f : 0.f;
            float vx1 = ((unsigned)(x0 + 1) < 128u) ? 1.f : 0.f;
            float w00 = (1.f - ddy) * (1.f - ddx) * vy0 * vx0;
            float w01 = (1.f - ddy) * ddx * vy0 * vx1;
            float w10 = ddy * (1.f - ddx) * vy1 * vx0;
            float w11 = ddy * ddx * vy1 * vx1;
            int y0c = min(max(y0, 0), 127), y1c = min(max(y0 + 1, 0), 127);
            int x0c = min(max(x0, 0), 127), x1c = min(max(x0 + 1, 0), 127);
            int xb = min(max(x0, 0), 126);
            bool sel0 = (x0c == xb), sel1 = (x1c == xb);
            const short* plg = plg0 + (size_t)gg * 65536;
            s16x8 pr0 = *(const s16x8*)(plg + (y0c * 128 + xb) * 4);
            s16x8 pr1 = *(const s16x8*)(plg + (y1c * 128 + xb) * 4);
            #pragma unroll
            for (int cc = 0; cc < 4; ++cc) {
                float v00 = b2f(sel0 ? pr0[cc] : pr0[4 + cc]);
                float v01 = b2f(sel1 ? pr0[cc] : pr0[4 + cc]);
                float v10 = b2f(sel0 ? pr1[cc] : pr1[4 + cc]);
                float v11 = b2f(sel1 ? pr1[cc] : pr1[4 + cc]);
                float sv = w00 * v00 + w01 * v01 + w10 * v10 + w11 * v11;
                r01[gg >> 1][(gg & 1) * 4 + cc] = f2bf(sv * mk);
            }
        }
        // write samples: row xt, chunks sg*2, sg*2+1 (XOR swizzle)
        *(s16x8*)((char*)smp + xt * 128 + (((sg * 2 + 0) ^ (xt & 7)) << 4)) = r01[0];
        *(s16x8*)((char*)smp + xt * 128 + (((sg * 2 + 1) ^ (xt & 7)) << 4)) = r01[1];
        // stage A (conv-proven pattern) + prefetch next tap
        *(i32x4*)((char*)aS + aoc * 128 + ((ac8 ^ (aoc & 7)) << 4)) = sa0;
        *(i32x4*)((char*)aS + (aoc + 32) * 128 + ((ac8 ^ ((aoc + 32) & 7)) << 4)) = sa1;
        if (tap < 8) {
            sa0 = *(const i32x4*)(dcwT + (size_t)aoc * 576 + (tap + 1) * 64 + ac8 * 8);
            sa1 = *(const i32x4*)(dcwT + (size_t)(aoc + 32) * 576 + (tap + 1) * 64 + ac8 * 8);
        }
        __syncthreads();  // smp + aS ready

        #pragma unroll
        for (int ih = 0; ih < 2; ++ih) {
            int slot = ih * 4 + q;
            s16x8 bf = *(const s16x8*)((const char*)smp + brow * 128 + ((slot ^ (brow & 7)) << 4));
            #pragma unroll
            for (int m = 0; m < 4; ++m) {
                int ocl = m * 16 + c;
                s16x8 a = *(const s16x8*)((const char*)aS + ocl * 128 + ((slot ^ (ocl & 7)) << 4));
                acc[m] = __builtin_amdgcn_mfma_f32_16x16x32_bf16(a, bf, acc[m], 0, 0, 0);
            }
        }
        __syncthreads();  // done reading smp/aS
    }

    #pragma unroll
    for (int m = 0; m < 4; ++m) {
        int o0 = m * 16 + q * 4;
        f32x4 bv = *(const f32x4*)(dcb + o0);
        f32x4 v = acc[m] + bv;
        int xo = xh + sg * 16 + c;
        #pragma unroll
        for (int j = 0; j < 4; ++j) {
            float t = v[j];
            t = t >= 0.f ? t : 0.1f * t;
            out[((size_t)n * 64 + o0 + j) * 16384 + y * 128 + xo] = t;
        }
    }
}

// ---------------------------------------------------------------------------
extern "C" void kernel_launch(void* const* d_in, const int* in_sizes, int n_in,
                              void* d_out, int out_size, void* d_ws, size_t ws_size,
                              hipStream_t stream)
{
    const float* nbr  = (const float*)d_in[0];
    const float* ref  = (const float*)d_in[1];
    const float* flow = (const float*)d_in[2];
    const float* w1   = (const float*)d_in[3];
    const float* b1   = (const float*)d_in[4];
    const float* w2   = (const float*)d_in[5];
    const float* b2   = (const float*)d_in[6];
    const float* w3   = (const float*)d_in[7];
    const float* b3   = (const float*)d_in[8];
    const float* w4   = (const float*)d_in[9];
    const float* b4   = (const float*)d_in[10];
    const float* dcw  = (const float*)d_in[11];
    const float* dcb  = (const float*)d_in[12];
    float* out = (float*)d_out;
    char* ws = (char*)d_ws;

    // ws layout (bytes), peak 91.23 MB (proven rounds 6/8/13/14/18).
    short* nbrG   = (short*)ws;
    short* wpool  = (short*)(ws + 16777216);
    short* warped = (short*)(ws + 17825792);
    short* refH   = (short*)(ws + 34603008);
    float* h1p    = (float*)(ws + 51380224);
    int*   offP   = (int*)(ws + 17825792);
    short* maskP  = (short*)(ws + 55574528);
    short* h3     = (short*)(ws + 74448896);
    short* h1     = warped;
    short* h2     = refH;

    short* wT1a = wpool;            // w1 ic 0-63
    short* wT1b = wpool + 36864;    // w1 ic 64-127
    short* wT2  = wpool + 73728;
    short* wT3  = wpool + 110592;
    short* wT4  = wpool + 147456;   // [448][9][64]
    short* dcwT = wpool + 405504;

    k_wt_all<<<1728, 256, 0, stream>>>(w1, w2, w3, w4, dcw, wpool);
    k_nhwc2<<<1024, 256, 0, stream>>>(nbr, ref, nbrG, refH);
    k_backwarp<<<2048, 256, 0, stream>>>(nbrG, flow, warped);

    // conv1 as two IC-64 passes
    k_conv<0><<<1024, 256, 0, stream>>>(warped, wT1a, nullptr, h1p, nullptr, nullptr, nullptr, nullptr, 0);
    k_conv<1><<<1024, 256, 0, stream>>>(refH, wT1b, b1, h1p, h1, nullptr, nullptr, nullptr, 0);
    k_conv<2><<<1024, 256, 0, stream>>>(h1, wT2, b2, nullptr, h2, nullptr, nullptr, nullptr, 0);
    k_conv<2><<<1024, 256, 0, stream>>>(h2, wT3, b3, nullptr, h3, nullptr, nullptr, nullptr, 0);

    // conv4 + DCN in 4-image chunks
    for (int n0 = 0; n0 < 8; n0 += 4) {
        dim3 g4(512, 7);
        k_conv<3><<<g4, 256, 0, stream>>>(h3, wT4, b4, nullptr, nullptr, offP, maskP, flow, n0);
        k_dcn<<<1024, 256, 0, stream>>>(offP, maskP, nbrG, dcwT, dcb, out, n0);
    }
}

// Round 22
// 320.415 us; speedup vs baseline: 1.1148x; 1.0401x over previous
//
#include <hip/hip_runtime.h>
#include <math.h>

#define H 128
#define W 128
#define NB 8
#define NFC 64

typedef __attribute__((ext_vector_type(8))) short s16x8;
typedef __attribute__((ext_vector_type(4))) short s16x4;
typedef __attribute__((ext_vector_type(4))) float f32x4;
typedef __attribute__((ext_vector_type(4))) int   i32x4;
typedef __attribute__((ext_vector_type(2))) int   i32x2;

__device__ __forceinline__ float b2f(short s) {
    return __uint_as_float(((unsigned)(unsigned short)s) << 16);
}
__device__ __forceinline__ short f2bf(float f) {
    unsigned u = __float_as_uint(f);
    u += 0x7FFF + ((u >> 16) & 1);
    return (short)(u >> 16);
}
__device__ __forceinline__ short f2h(float f) {
    _Float16 h = (_Float16)f;
    return __builtin_bit_cast(short, h);
}
__device__ __forceinline__ float h2f(short s) {
    return (float)__builtin_bit_cast(_Float16, s);
}

// ---------------------------------------------------------------------------
// all weight transforms in one launch -> wpool bf16 [768][9][64]
// ---------------------------------------------------------------------------
__global__ __launch_bounds__(256) void k_wt_all(
    const float* __restrict__ w1, const float* __restrict__ w2,
    const float* __restrict__ w3, const float* __restrict__ w4,
    const float* __restrict__ dcw, short* __restrict__ wp)
{
    int idx = blockIdx.x * 256 + threadIdx.x;   // < 442368
    int u = idx / 576;
    int r = idx - u * 576;
    int t = r >> 6, i = r & 63;
    float v;
    if (u < 128) {
        int o = u & 63, icoff = (u >> 6) << 6;
        v = w1[((size_t)(o * 128) + icoff + i) * 9 + t];
    } else if (u < 192) {
        int o = u - 128;
        v = w2[((size_t)(o * 64) + i) * 9 + t];
    } else if (u < 256) {
        int o = u - 192;
        v = w3[((size_t)(o * 64) + i) * 9 + t];
    } else if (u < 704) {
        int o = u - 256;
        v = (o < 432) ? w4[((size_t)(o * 64) + i) * 9 + t] : 0.f;
    } else {
        int o = u - 704;
        v = dcw[((size_t)(o * 64) + i) * 9 + t];
    }
    wp[idx] = f2bf(v);
}

// ---------------------------------------------------------------------------
// NCHW fp32 -> (nbr: g-planar bf16 [n][16][128][128][4]) and (ref: NHWC bf16)
// ---------------------------------------------------------------------------
__global__ __launch_bounds__(256) void k_nhwc2(const float* __restrict__ nbr,
                                               const float* __restrict__ ref,
                                               short* __restrict__ nbrG,
                                               short* __restrict__ refH)
{
    int px = blockIdx.x * 256 + threadIdx.x;
    bool isNbr = (px < 131072);
    const float* src;
    if (isNbr) { src = nbr; }
    else       { src = ref; px -= 131072; }
    int n = px >> 14;
    int sp = px & 16383;
    const float* s = src + (size_t)n * 64 * 16384 + sp;
    unsigned pk[32];
    #pragma unroll
    for (int c = 0; c < 32; ++c) {
        float v0 = s[(size_t)(2 * c) * 16384];
        float v1 = s[(size_t)(2 * c + 1) * 16384];
        pk[c] = (unsigned)(unsigned short)f2bf(v0) |
                ((unsigned)(unsigned short)f2bf(v1) << 16);
    }
    if (isNbr) {
        #pragma unroll
        for (int g = 0; g < 16; ++g) {
            i32x2 t;
            t[0] = pk[2 * g]; t[1] = pk[2 * g + 1];
            *(i32x2*)(nbrG + ((size_t)(n * 16 + g) * 16384 + sp) * 4) = t;
        }
    } else {
        i32x4* d = (i32x4*)(refH + (size_t)(n * 16384 + sp) * 64);
        #pragma unroll
        for (int qq = 0; qq < 8; ++qq) {
            i32x4 t;
            t[0] = pk[4 * qq]; t[1] = pk[4 * qq + 1];
            t[2] = pk[4 * qq + 2]; t[3] = pk[4 * qq + 3];
            d[qq] = t;
        }
    }
}

// ---------------------------------------------------------------------------
// backwarp: nbrG (g-planar bf16) + flow -> warped (NHWC bf16)
// ---------------------------------------------------------------------------
__global__ __launch_bounds__(256) void k_backwarp(const short* __restrict__ nbrG,
                                                  const float* __restrict__ flow,
                                                  short* __restrict__ warped)
{
    int idx = blockIdx.x * 256 + threadIdx.x;
    int px = idx >> 2, qt = idx & 3;
    int n = px >> 14;
    int x = px & 127, y = (px >> 7) & 127;
    float fx = flow[(size_t)(n * 2 + 0) * 16384 + y * 128 + x];
    float fy = flow[(size_t)(n * 2 + 1) * 16384 + y * 128 + x];
    float pxf = (float)x + fx, pyf = (float)y + fy;
    float x0f = floorf(pxf), y0f = floorf(pyf);
    int x0 = (int)x0f, y0 = (int)y0f;
    float dx = pxf - x0f, dy = pyf - y0f;
    float vy0 = ((unsigned)y0 < 128u) ? 1.f : 0.f;
    float vy1 = ((unsigned)(y0 + 1) < 128u) ? 1.f : 0.f;
    float vx0 = ((unsigned)x0 < 128u) ? 1.f : 0.f;
    float vx1 = ((unsigned)(x0 + 1) < 128u) ? 1.f : 0.f;
    float w00 = (1.f - dy) * (1.f - dx) * vy0 * vx0;
    float w01 = (1.f - dy) * dx * vy0 * vx1;
    float w10 = dy * (1.f - dx) * vy1 * vx0;
    float w11 = dy * dx * vy1 * vx1;
    int y0c = min(max(y0, 0), 127), y1c = min(max(y0 + 1, 0), 127);
    int x0c = min(max(x0, 0), 127), x1c = min(max(x0 + 1, 0), 127);
    int xb = min(max(x0, 0), 126);
    bool s0 = (x0c == xb), s1 = (x1c == xb);

    const short* plbase = nbrG + (size_t)n * 16 * 65536;
    s16x8 r0, r1;
    #pragma unroll
    for (int pg = 0; pg < 4; ++pg) {
        const short* pl = plbase + (size_t)(qt * 4 + pg) * 65536;
        s16x8 p0 = *(const s16x8*)(pl + (y0c * 128 + xb) * 4);
        s16x8 p1 = *(const s16x8*)(pl + (y1c * 128 + xb) * 4);
        #pragma unroll
        for (int cc = 0; cc < 4; ++cc) {
            float v00 = b2f(s0 ? p0[cc] : p0[4 + cc]);
            float v01 = b2f(s1 ? p0[cc] : p0[4 + cc]);
            float v10 = b2f(s0 ? p1[cc] : p1[4 + cc]);
            float v11 = b2f(s1 ? p1[cc] : p1[4 + cc]);
            float v = w00 * v00 + w01 * v01 + w10 * v10 + w11 * v11;
            short res = f2bf(v);
            if (pg < 2) r0[pg * 4 + cc] = res;
            else        r1[(pg - 2) * 4 + cc] = res;
        }
    }
    short* o = warped + (size_t)px * 64 + qt * 16;
    *(s16x8*)o = r0;
    *(s16x8*)(o + 8) = r1;
}

// ---------------------------------------------------------------------------
// MFMA conv3x3, IC=64 (dbuf aS, 1 barrier/tap). ROW-STRIP patches:
// MFMA N-tile = 16 x-consecutive px of one row; wave wv owns rows 2wv,2wv+1.
// -> epilogue lanes write 16 consecutive px (offP 64B runs).
// MODE 3 epilogue writes G-PLANAR offset+mask planes (round-21).
// ---------------------------------------------------------------------------
template<int MODE>
__global__ __launch_bounds__(256) void k_conv(
    const short* __restrict__ in, const short* __restrict__ wT,
    const float* __restrict__ bias,
    float* __restrict__ partial, short* __restrict__ outB,
    int* __restrict__ offP, short* __restrict__ maskP,
    const float* __restrict__ flow, int n0)
{
    __shared__ __align__(16) short tileS[180 * 64];
    __shared__ __align__(16) short aS[2][64 * 64];

    int tid = threadIdx.x;
    int bid = blockIdx.x;
    int og = (MODE == 3) ? blockIdx.y : 0;
    int n  = (MODE == 3) ? (n0 + (bid >> 7)) : (bid >> 7);
    int tl = bid & 127;
    int bx = (tl & 7) << 4;
    int by = (tl >> 3) << 3;
    int ln = tid & 63, wv = tid >> 6;
    int c = ln & 15, q = ln >> 4;

    for (int i = tid; i < 1440; i += 256) {
        int pt = i >> 3, c16 = i & 7;
        int ty = pt / 18, tx = pt - ty * 18;
        int gy = by + ty - 1, gx = bx + tx - 1;
        i32x4 v = {0, 0, 0, 0};
        if ((unsigned)gy < 128u && (unsigned)gx < 128u)
            v = *(const i32x4*)(in + (((size_t)n * 128 + gy) * 128 + gx) * 64 + c16 * 8);
        *(i32x4*)((char*)tileS + pt * 128 + ((c16 ^ (pt & 7)) << 4)) = v;
    }

    const short* wbase = wT + ((MODE == 3) ? (size_t)og * 36864 : 0);
    int aoc = tid >> 3, ac8 = tid & 7;
    {
        i32x4 t0a = *(const i32x4*)(wbase + (size_t)aoc * 576 + ac8 * 8);
        i32x4 t0b = *(const i32x4*)(wbase + (size_t)(aoc + 32) * 576 + ac8 * 8);
        *(i32x4*)((char*)aS[0] + aoc * 128 + ((ac8 ^ (aoc & 7)) << 4)) = t0a;
        *(i32x4*)((char*)aS[0] + (aoc + 32) * 128 + ((ac8 ^ ((aoc + 32) & 7)) << 4)) = t0b;
    }
    i32x4 sa0 = *(const i32x4*)(wbase + (size_t)aoc * 576 + 64 + ac8 * 8);
    i32x4 sa1 = *(const i32x4*)(wbase + (size_t)(aoc + 32) * 576 + 64 + ac8 * 8);

    f32x4 acc[4][2];
    #pragma unroll
    for (int m = 0; m < 4; ++m) {
        acc[m][0] = (f32x4){0.f, 0.f, 0.f, 0.f};
        acc[m][1] = (f32x4){0.f, 0.f, 0.f, 0.f};
    }

    int row0 = 2 * wv, row1 = 2 * wv + 1;   // wave's two row-strip patches

    __syncthreads();  // tile + aS[0] ready

    for (int tap = 0; tap < 9; ++tap) {
        int cur = tap & 1;
        if (tap < 8) {
            *(i32x4*)((char*)aS[cur ^ 1] + aoc * 128 + ((ac8 ^ (aoc & 7)) << 4)) = sa0;
            *(i32x4*)((char*)aS[cur ^ 1] + (aoc + 32) * 128 + ((ac8 ^ ((aoc + 32) & 7)) << 4)) = sa1;
            if (tap < 7) {
                sa0 = *(const i32x4*)(wbase + (size_t)aoc * 576 + (tap + 2) * 64 + ac8 * 8);
                sa1 = *(const i32x4*)(wbase + (size_t)(aoc + 32) * 576 + (tap + 2) * 64 + ac8 * 8);
            }
        }

        int dty = tap / 3, dtx = tap - dty * 3;
        int pta = (row0 + dty) * 18 + c + dtx;
        int ptb = (row1 + dty) * 18 + c + dtx;
        #pragma unroll
        for (int ih = 0; ih < 2; ++ih) {
            int slot = ih * 4 + q;
            s16x8 bf0 = *(const s16x8*)((const char*)tileS + pta * 128 + ((slot ^ (pta & 7)) << 4));
            s16x8 bf1 = *(const s16x8*)((const char*)tileS + ptb * 128 + ((slot ^ (ptb & 7)) << 4));
            #pragma unroll
            for (int m = 0; m < 4; ++m) {
                int ocl = m * 16 + c;
                s16x8 a = *(const s16x8*)((const char*)aS[cur] + ocl * 128 + ((slot ^ (ocl & 7)) << 4));
                acc[m][0] = __builtin_amdgcn_mfma_f32_16x16x32_bf16(a, bf0, acc[m][0], 0, 0, 0);
                acc[m][1] = __builtin_amdgcn_mfma_f32_16x16x32_bf16(a, bf1, acc[m][1], 0, 0, 0);
            }
        }
        if (tap < 8) __syncthreads();
    }

    #pragma unroll
    for (int p = 0; p < 2; ++p) {
        int y = by + (p ? row1 : row0);
        int x = bx + c;
        size_t pxi = ((size_t)n * 128 + y) * 128 + x;
        float fy = 0.f, fx2 = 0.f;
        if (MODE == 3) {
            fy  = flow[(size_t)(n * 2 + 1) * 16384 + y * 128 + x];
            fx2 = flow[(size_t)(n * 2 + 0) * 16384 + y * 128 + x];
        }
        #pragma unroll
        for (int m = 0; m < 4; ++m) {
            int o0 = m * 16 + q * 4;
            f32x4 v = acc[m][p];
            if (MODE == 0) {
                *(f32x4*)(partial + pxi * 64 + o0) = v;
            } else if (MODE == 1 || MODE == 2) {
                f32x4 bv = *(const f32x4*)(bias + o0);
                if (MODE == 1) {
                    f32x4 pv = *(const f32x4*)(partial + pxi * 64 + o0);
                    v += pv;
                }
                v += bv;
                s16x4 r;
                #pragma unroll
                for (int j = 0; j < 4; ++j) {
                    float t = v[j];
                    t = t >= 0.f ? t : 0.1f * t;
                    r[j] = f2bf(t);
                }
                *(s16x4*)(outB + pxi * 64 + o0) = r;
            } else {  // MODE 3: g-planar offset+mask planes (x-coalesced)
                int oc4 = og * 64 + o0;
                if (oc4 < 432) {
                    f32x4 bv = *(const f32x4*)(bias + oc4);
                    v += bv;
                    size_t nrel = (size_t)(bid >> 7);
                    int pxl = y * 128 + x;
                    if (oc4 < 288) {
                        int gk0 = oc4 >> 1;
                        int g0 = gk0 / 9, t0 = gk0 - g0 * 9;
                        int gk1 = gk0 + 1;
                        int g1 = gk1 / 9, t1 = gk1 - g1 * 9;
                        unsigned pk0 = (unsigned)(unsigned short)f2h(v[0] + fy) |
                                       ((unsigned)(unsigned short)f2h(v[1] + fx2) << 16);
                        unsigned pk1 = (unsigned)(unsigned short)f2h(v[2] + fy) |
                                       ((unsigned)(unsigned short)f2h(v[3] + fx2) << 16);
                        offP[((nrel * 9 + t0) * 16 + g0) * 16384 + (size_t)pxl] = (int)pk0;
                        offP[((nrel * 9 + t1) * 16 + g1) * 16384 + (size_t)pxl] = (int)pk1;
                    } else {
                        int gkb = oc4 - 288;
                        #pragma unroll
                        for (int j = 0; j < 4; ++j) {
                            int gk = gkb + j;
                            int g = gk / 9, t = gk - g * 9;
                            maskP[((nrel * 9 + t) * 16 + g) * 16384 + (size_t)pxl] =
                                f2h(1.f / (1.f + expf(-v[j])));
                        }
                    }
                }
            }
        }
    }
}

// ---------------------------------------------------------------------------
// DCN: block = 64-pixel row strip, 4 waves (round-21-proven, unchanged).
// ---------------------------------------------------------------------------
__global__ __launch_bounds__(256) void k_dcn(
    const int* __restrict__ offP, const short* __restrict__ maskP,
    const short* __restrict__ nbrG, const short* __restrict__ dcwT,
    const float* __restrict__ dcb, float* __restrict__ out, int n0)
{
    __shared__ __align__(16) short smp[64 * 64];  // [px][ic], 16B-chunk XOR swizzle
    __shared__ __align__(16) short aS[64 * 64];

    int tid = threadIdx.x;
    int bid = blockIdx.x;            // 4 img * 256 strips
    int nrel = bid >> 8;
    int rb = bid & 255;
    int y = rb >> 1;
    int xh = (rb & 1) << 6;
    int n = n0 + nrel;

    int xt = tid & 63;               // x within strip (sample phase)
    int sg = tid >> 6;               // wave id = g-group
    int ln = tid & 63, c = ln & 15, q = ln >> 4;
    int x = xh + xt;
    int pxl = y * 128 + x;

    int aoc = tid >> 3, ac8 = tid & 7;
    i32x4 sa0 = *(const i32x4*)(dcwT + (size_t)aoc * 576 + ac8 * 8);
    i32x4 sa1 = *(const i32x4*)(dcwT + (size_t)(aoc + 32) * 576 + ac8 * 8);

    const short* plg0 = nbrG + (size_t)(n * 16 + sg * 4) * 65536;

    f32x4 acc[4];
    #pragma unroll
    for (int m = 0; m < 4; ++m) acc[m] = (f32x4){0.f, 0.f, 0.f, 0.f};

    int brow = sg * 16 + c;          // wave's output pixel row in smp

    for (int tap = 0; tap < 9; ++tap) {
        int dty = tap / 3 - 1, dtx = tap - (tap / 3) * 3 - 1;
        size_t pbase = ((size_t)(nrel * 9 + tap) * 16 + sg * 4) * 16384 + pxl;
        i32x4 dd4;
        s16x4 mk4;
        #pragma unroll
        for (int gg = 0; gg < 4; ++gg) {
            dd4[gg] = offP[pbase + (size_t)gg * 16384];
            mk4[gg] = maskP[pbase + (size_t)gg * 16384];
        }

        s16x8 r01[2];
        #pragma unroll
        for (int gg = 0; gg < 4; ++gg) {
            float dyv = h2f((short)(dd4[gg] & 0xffff));
            float dxv = h2f((short)(((unsigned)dd4[gg]) >> 16));
            float mk  = h2f(mk4[gg]);
            float sy = (float)(y + dty) + dyv;
            float sx = (float)(x + dtx) + dxv;
            float y0f = floorf(sy), x0f = floorf(sx);
            int y0 = (int)y0f, x0 = (int)x0f;
            float ddy = sy - y0f, ddx = sx - x0f;
            float vy0 = ((unsigned)y0 < 128u) ? 1.f : 0.f;
            float vy1 = ((unsigned)(y0 + 1) < 128u) ? 1.f : 0.f;
            float vx0 = ((unsigned)x0 < 128u) ? 1.f : 0.f;
            float vx1 = ((unsigned)(x0 + 1) < 128u) ? 1.f : 0.f;
            float w00 = (1.f - ddy) * (1.f - ddx) * vy0 * vx0;
            float w01 = (1.f - ddy) * ddx * vy0 * vx1;
            float w10 = ddy * (1.f - ddx) * vy1 * vx0;
            float w11 = ddy * ddx * vy1 * vx1;
            int y0c = min(max(y0, 0), 127), y1c = min(max(y0 + 1, 0), 127);
            int x0c = min(max(x0, 0), 127), x1c = min(max(x0 + 1, 0), 127);
            int xb = min(max(x0, 0), 126);
            bool sel0 = (x0c == xb), sel1 = (x1c == xb);
            const short* plg = plg0 + (size_t)gg * 65536;
            s16x8 pr0 = *(const s16x8*)(plg + (y0c * 128 + xb) * 4);
            s16x8 pr1 = *(const s16x8*)(plg + (y1c * 128 + xb) * 4);
            #pragma unroll
            for (int cc = 0; cc < 4; ++cc) {
                float v00 = b2f(sel0 ? pr0[cc] : pr0[4 + cc]);
                float v01 = b2f(sel1 ? pr0[cc] : pr0[4 + cc]);
                float v10 = b2f(sel0 ? pr1[cc] : pr1[4 + cc]);
                float v11 = b2f(sel1 ? pr1[cc] : pr1[4 + cc]);
                float sv = w00 * v00 + w01 * v01 + w10 * v10 + w11 * v11;
                r01[gg >> 1][(gg & 1) * 4 + cc] = f2bf(sv * mk);
            }
        }
        // write samples: row xt, chunks sg*2, sg*2+1 (XOR swizzle)
        *(s16x8*)((char*)smp + xt * 128 + (((sg * 2 + 0) ^ (xt & 7)) << 4)) = r01[0];
        *(s16x8*)((char*)smp + xt * 128 + (((sg * 2 + 1) ^ (xt & 7)) << 4)) = r01[1];
        // stage A (conv-proven pattern) + prefetch next tap
        *(i32x4*)((char*)aS + aoc * 128 + ((ac8 ^ (aoc & 7)) << 4)) = sa0;
        *(i32x4*)((char*)aS + (aoc + 32) * 128 + ((ac8 ^ ((aoc + 32) & 7)) << 4)) = sa1;
        if (tap < 8) {
            sa0 = *(const i32x4*)(dcwT + (size_t)aoc * 576 + (tap + 1) * 64 + ac8 * 8);
            sa1 = *(const i32x4*)(dcwT + (size_t)(aoc + 32) * 576 + (tap + 1) * 64 + ac8 * 8);
        }
        __syncthreads();  // smp + aS ready

        #pragma unroll
        for (int ih = 0; ih < 2; ++ih) {
            int slot = ih * 4 + q;
            s16x8 bf = *(const s16x8*)((const char*)smp + brow * 128 + ((slot ^ (brow & 7)) << 4));
            #pragma unroll
            for (int m = 0; m < 4; ++m) {
                int ocl = m * 16 + c;
                s16x8 a = *(const s16x8*)((const char*)aS + ocl * 128 + ((slot ^ (ocl & 7)) << 4));
                acc[m] = __builtin_amdgcn_mfma_f32_16x16x32_bf16(a, bf, acc[m], 0, 0, 0);
            }
        }
        __syncthreads();  // done reading smp/aS
    }

    #pragma unroll
    for (int m = 0; m < 4; ++m) {
        int o0 = m * 16 + q * 4;
        f32x4 bv = *(const f32x4*)(dcb + o0);
        f32x4 v = acc[m] + bv;
        int xo = xh + sg * 16 + c;
        #pragma unroll
        for (int j = 0; j < 4; ++j) {
            float t = v[j];
            t = t >= 0.f ? t : 0.1f * t;
            out[((size_t)n * 64 + o0 + j) * 16384 + y * 128 + xo] = t;
        }
    }
}

// ---------------------------------------------------------------------------
extern "C" void kernel_launch(void* const* d_in, const int* in_sizes, int n_in,
                              void* d_out, int out_size, void* d_ws, size_t ws_size,
                              hipStream_t stream)
{
    const float* nbr  = (const float*)d_in[0];
    const float* ref  = (const float*)d_in[1];
    const float* flow = (const float*)d_in[2];
    const float* w1   = (const float*)d_in[3];
    const float* b1   = (const float*)d_in[4];
    const float* w2   = (const float*)d_in[5];
    const float* b2   = (const float*)d_in[6];
    const float* w3   = (const float*)d_in[7];
    const float* b3   = (const float*)d_in[8];
    const float* w4   = (const float*)d_in[9];
    const float* b4   = (const float*)d_in[10];
    const float* dcw  = (const float*)d_in[11];
    const float* dcb  = (const float*)d_in[12];
    float* out = (float*)d_out;
    char* ws = (char*)d_ws;

    // ws layout (bytes), peak 91.23 MB (proven rounds 6/8/13/14/18/21).
    short* nbrG   = (short*)ws;
    short* wpool  = (short*)(ws + 16777216);
    short* warped = (short*)(ws + 17825792);
    short* refH   = (short*)(ws + 34603008);
    float* h1p    = (float*)(ws + 51380224);
    int*   offP   = (int*)(ws + 17825792);
    short* maskP  = (short*)(ws + 55574528);
    short* h3     = (short*)(ws + 74448896);
    short* h1     = warped;
    short* h2     = refH;

    short* wT1a = wpool;            // w1 ic 0-63
    short* wT1b = wpool + 36864;    // w1 ic 64-127
    short* wT2  = wpool + 73728;
    short* wT3  = wpool + 110592;
    short* wT4  = wpool + 147456;   // [448][9][64]
    short* dcwT = wpool + 405504;

    k_wt_all<<<1728, 256, 0, stream>>>(w1, w2, w3, w4, dcw, wpool);
    k_nhwc2<<<1024, 256, 0, stream>>>(nbr, ref, nbrG, refH);
    k_backwarp<<<2048, 256, 0, stream>>>(nbrG, flow, warped);

    // conv1 as two IC-64 passes
    k_conv<0><<<1024, 256, 0, stream>>>(warped, wT1a, nullptr, h1p, nullptr, nullptr, nullptr, nullptr, 0);
    k_conv<1><<<1024, 256, 0, stream>>>(refH, wT1b, b1, h1p, h1, nullptr, nullptr, nullptr, 0);
    k_conv<2><<<1024, 256, 0, stream>>>(h1, wT2, b2, nullptr, h2, nullptr, nullptr, nullptr, 0);
    k_conv<2><<<1024, 256, 0, stream>>>(h2, wT3, b3, nullptr, h3, nullptr, nullptr, nullptr, 0);

    // conv4 + DCN in 4-image chunks
    for (int n0 = 0; n0 < 8; n0 += 4) {
        dim3 g4(512, 7);
        k_conv<3><<<g4, 256, 0, stream>>>(h3, wT4, b4, nullptr, nullptr, offP, maskP, flow, n0);
        k_dcn<<<1024, 256, 0, stream>>>(offP, maskP, nbrG, dcwT, dcb, out, n0);
    }
}

// Round 23
// 302.876 us; speedup vs baseline: 1.1794x; 1.0579x over previous
//
#include <hip/hip_runtime.h>
#include <math.h>

#define H 128
#define W 128
#define NB 8
#define NFC 64

typedef __attribute__((ext_vector_type(8))) short s16x8;
typedef __attribute__((ext_vector_type(4))) short s16x4;
typedef __attribute__((ext_vector_type(4))) float f32x4;
typedef __attribute__((ext_vector_type(4))) int   i32x4;
typedef __attribute__((ext_vector_type(2))) int   i32x2;

__device__ __forceinline__ float b2f(short s) {
    return __uint_as_float(((unsigned)(unsigned short)s) << 16);
}
__device__ __forceinline__ short f2bf(float f) {
    unsigned u = __float_as_uint(f);
    u += 0x7FFF + ((u >> 16) & 1);
    return (short)(u >> 16);
}
__device__ __forceinline__ short f2h(float f) {
    _Float16 h = (_Float16)f;
    return __builtin_bit_cast(short, h);
}
__device__ __forceinline__ float h2f(short s) {
    return (float)__builtin_bit_cast(_Float16, s);
}

// ---------------------------------------------------------------------------
// all weight transforms in one launch -> wpool bf16 [768][9][64]
// ---------------------------------------------------------------------------
__global__ __launch_bounds__(256) void k_wt_all(
    const float* __restrict__ w1, const float* __restrict__ w2,
    const float* __restrict__ w3, const float* __restrict__ w4,
    const float* __restrict__ dcw, short* __restrict__ wp)
{
    int idx = blockIdx.x * 256 + threadIdx.x;   // < 442368
    int u = idx / 576;
    int r = idx - u * 576;
    int t = r >> 6, i = r & 63;
    float v;
    if (u < 128) {
        int o = u & 63, icoff = (u >> 6) << 6;
        v = w1[((size_t)(o * 128) + icoff + i) * 9 + t];
    } else if (u < 192) {
        int o = u - 128;
        v = w2[((size_t)(o * 64) + i) * 9 + t];
    } else if (u < 256) {
        int o = u - 192;
        v = w3[((size_t)(o * 64) + i) * 9 + t];
    } else if (u < 704) {
        int o = u - 256;
        v = (o < 432) ? w4[((size_t)(o * 64) + i) * 9 + t] : 0.f;
    } else {
        int o = u - 704;
        v = dcw[((size_t)(o * 64) + i) * 9 + t];
    }
    wp[idx] = f2bf(v);
}

// ---------------------------------------------------------------------------
// NCHW fp32 -> (nbr: g-planar bf16 [n][16][128][128][4]) and (ref: NHWC bf16)
// ---------------------------------------------------------------------------
__global__ __launch_bounds__(256) void k_nhwc2(const float* __restrict__ nbr,
                                               const float* __restrict__ ref,
                                               short* __restrict__ nbrG,
                                               short* __restrict__ refH)
{
    int px = blockIdx.x * 256 + threadIdx.x;
    bool isNbr = (px < 131072);
    const float* src;
    if (isNbr) { src = nbr; }
    else       { src = ref; px -= 131072; }
    int n = px >> 14;
    int sp = px & 16383;
    const float* s = src + (size_t)n * 64 * 16384 + sp;
    unsigned pk[32];
    #pragma unroll
    for (int c = 0; c < 32; ++c) {
        float v0 = s[(size_t)(2 * c) * 16384];
        float v1 = s[(size_t)(2 * c + 1) * 16384];
        pk[c] = (unsigned)(unsigned short)f2bf(v0) |
                ((unsigned)(unsigned short)f2bf(v1) << 16);
    }
    if (isNbr) {
        #pragma unroll
        for (int g = 0; g < 16; ++g) {
            i32x2 t;
            t[0] = pk[2 * g]; t[1] = pk[2 * g + 1];
            *(i32x2*)(nbrG + ((size_t)(n * 16 + g) * 16384 + sp) * 4) = t;
        }
    } else {
        i32x4* d = (i32x4*)(refH + (size_t)(n * 16384 + sp) * 64);
        #pragma unroll
        for (int qq = 0; qq < 8; ++qq) {
            i32x4 t;
            t[0] = pk[4 * qq]; t[1] = pk[4 * qq + 1];
            t[2] = pk[4 * qq + 2]; t[3] = pk[4 * qq + 3];
            d[qq] = t;
        }
    }
}

// ---------------------------------------------------------------------------
// backwarp: nbrG (g-planar bf16) + flow -> warped (NHWC bf16)
// ---------------------------------------------------------------------------
__global__ __launch_bounds__(256) void k_backwarp(const short* __restrict__ nbrG,
                                                  const float* __restrict__ flow,
                                                  short* __restrict__ warped)
{
    int idx = blockIdx.x * 256 + threadIdx.x;
    int px = idx >> 2, qt = idx & 3;
    int n = px >> 14;
    int x = px & 127, y = (px >> 7) & 127;
    float fx = flow[(size_t)(n * 2 + 0) * 16384 + y * 128 + x];
    float fy = flow[(size_t)(n * 2 + 1) * 16384 + y * 128 + x];
    float pxf = (float)x + fx, pyf = (float)y + fy;
    float x0f = floorf(pxf), y0f = floorf(pyf);
    int x0 = (int)x0f, y0 = (int)y0f;
    float dx = pxf - x0f, dy = pyf - y0f;
    float vy0 = ((unsigned)y0 < 128u) ? 1.f : 0.f;
    float vy1 = ((unsigned)(y0 + 1) < 128u) ? 1.f : 0.f;
    float vx0 = ((unsigned)x0 < 128u) ? 1.f : 0.f;
    float vx1 = ((unsigned)(x0 + 1) < 128u) ? 1.f : 0.f;
    float w00 = (1.f - dy) * (1.f - dx) * vy0 * vx0;
    float w01 = (1.f - dy) * dx * vy0 * vx1;
    float w10 = dy * (1.f - dx) * vy1 * vx0;
    float w11 = dy * dx * vy1 * vx1;
    int y0c = min(max(y0, 0), 127), y1c = min(max(y0 + 1, 0), 127);
    int x0c = min(max(x0, 0), 127), x1c = min(max(x0 + 1, 0), 127);
    int xb = min(max(x0, 0), 126);
    bool s0 = (x0c == xb), s1 = (x1c == xb);

    const short* plbase = nbrG + (size_t)n * 16 * 65536;
    s16x8 r0, r1;
    #pragma unroll
    for (int pg = 0; pg < 4; ++pg) {
        const short* pl = plbase + (size_t)(qt * 4 + pg) * 65536;
        s16x8 p0 = *(const s16x8*)(pl + (y0c * 128 + xb) * 4);
        s16x8 p1 = *(const s16x8*)(pl + (y1c * 128 + xb) * 4);
        #pragma unroll
        for (int cc = 0; cc < 4; ++cc) {
            float v00 = b2f(s0 ? p0[cc] : p0[4 + cc]);
            float v01 = b2f(s1 ? p0[cc] : p0[4 + cc]);
            float v10 = b2f(s0 ? p1[cc] : p1[4 + cc]);
            float v11 = b2f(s1 ? p1[cc] : p1[4 + cc]);
            float v = w00 * v00 + w01 * v01 + w10 * v10 + w11 * v11;
            short res = f2bf(v);
            if (pg < 2) r0[pg * 4 + cc] = res;
            else        r1[(pg - 2) * 4 + cc] = res;
        }
    }
    short* o = warped + (size_t)px * 64 + qt * 16;
    *(s16x8*)o = r0;
    *(s16x8*)(o + 8) = r1;
}

// ---------------------------------------------------------------------------
// MFMA conv3x3, IC=64 (dbuf aS, 1 barrier/tap, row-strip patches; R22-proven).
// MODE 3 epilogue writes G-PLANAR offset+mask planes.
// ---------------------------------------------------------------------------
template<int MODE>
__global__ __launch_bounds__(256) void k_conv(
    const short* __restrict__ in, const short* __restrict__ wT,
    const float* __restrict__ bias,
    float* __restrict__ partial, short* __restrict__ outB,
    int* __restrict__ offP, short* __restrict__ maskP,
    const float* __restrict__ flow, int n0)
{
    __shared__ __align__(16) short tileS[180 * 64];
    __shared__ __align__(16) short aS[2][64 * 64];

    int tid = threadIdx.x;
    int bid = blockIdx.x;
    int og = (MODE == 3) ? blockIdx.y : 0;
    int n  = (MODE == 3) ? (n0 + (bid >> 7)) : (bid >> 7);
    int tl = bid & 127;
    int bx = (tl & 7) << 4;
    int by = (tl >> 3) << 3;
    int ln = tid & 63, wv = tid >> 6;
    int c = ln & 15, q = ln >> 4;

    for (int i = tid; i < 1440; i += 256) {
        int pt = i >> 3, c16 = i & 7;
        int ty = pt / 18, tx = pt - ty * 18;
        int gy = by + ty - 1, gx = bx + tx - 1;
        i32x4 v = {0, 0, 0, 0};
        if ((unsigned)gy < 128u && (unsigned)gx < 128u)
            v = *(const i32x4*)(in + (((size_t)n * 128 + gy) * 128 + gx) * 64 + c16 * 8);
        *(i32x4*)((char*)tileS + pt * 128 + ((c16 ^ (pt & 7)) << 4)) = v;
    }

    const short* wbase = wT + ((MODE == 3) ? (size_t)og * 36864 : 0);
    int aoc = tid >> 3, ac8 = tid & 7;
    {
        i32x4 t0a = *(const i32x4*)(wbase + (size_t)aoc * 576 + ac8 * 8);
        i32x4 t0b = *(const i32x4*)(wbase + (size_t)(aoc + 32) * 576 + ac8 * 8);
        *(i32x4*)((char*)aS[0] + aoc * 128 + ((ac8 ^ (aoc & 7)) << 4)) = t0a;
        *(i32x4*)((char*)aS[0] + (aoc + 32) * 128 + ((ac8 ^ ((aoc + 32) & 7)) << 4)) = t0b;
    }
    i32x4 sa0 = *(const i32x4*)(wbase + (size_t)aoc * 576 + 64 + ac8 * 8);
    i32x4 sa1 = *(const i32x4*)(wbase + (size_t)(aoc + 32) * 576 + 64 + ac8 * 8);

    f32x4 acc[4][2];
    #pragma unroll
    for (int m = 0; m < 4; ++m) {
        acc[m][0] = (f32x4){0.f, 0.f, 0.f, 0.f};
        acc[m][1] = (f32x4){0.f, 0.f, 0.f, 0.f};
    }

    int row0 = 2 * wv, row1 = 2 * wv + 1;   // wave's two row-strip patches

    __syncthreads();  // tile + aS[0] ready

    for (int tap = 0; tap < 9; ++tap) {
        int cur = tap & 1;
        if (tap < 8) {
            *(i32x4*)((char*)aS[cur ^ 1] + aoc * 128 + ((ac8 ^ (aoc & 7)) << 4)) = sa0;
            *(i32x4*)((char*)aS[cur ^ 1] + (aoc + 32) * 128 + ((ac8 ^ ((aoc + 32) & 7)) << 4)) = sa1;
            if (tap < 7) {
                sa0 = *(const i32x4*)(wbase + (size_t)aoc * 576 + (tap + 2) * 64 + ac8 * 8);
                sa1 = *(const i32x4*)(wbase + (size_t)(aoc + 32) * 576 + (tap + 2) * 64 + ac8 * 8);
            }
        }

        int dty = tap / 3, dtx = tap - dty * 3;
        int pta = (row0 + dty) * 18 + c + dtx;
        int ptb = (row1 + dty) * 18 + c + dtx;
        #pragma unroll
        for (int ih = 0; ih < 2; ++ih) {
            int slot = ih * 4 + q;
            s16x8 bf0 = *(const s16x8*)((const char*)tileS + pta * 128 + ((slot ^ (pta & 7)) << 4));
            s16x8 bf1 = *(const s16x8*)((const char*)tileS + ptb * 128 + ((slot ^ (ptb & 7)) << 4));
            #pragma unroll
            for (int m = 0; m < 4; ++m) {
                int ocl = m * 16 + c;
                s16x8 a = *(const s16x8*)((const char*)aS[cur] + ocl * 128 + ((slot ^ (ocl & 7)) << 4));
                acc[m][0] = __builtin_amdgcn_mfma_f32_16x16x32_bf16(a, bf0, acc[m][0], 0, 0, 0);
                acc[m][1] = __builtin_amdgcn_mfma_f32_16x16x32_bf16(a, bf1, acc[m][1], 0, 0, 0);
            }
        }
        if (tap < 8) __syncthreads();
    }

    #pragma unroll
    for (int p = 0; p < 2; ++p) {
        int y = by + (p ? row1 : row0);
        int x = bx + c;
        size_t pxi = ((size_t)n * 128 + y) * 128 + x;
        float fy = 0.f, fx2 = 0.f;
        if (MODE == 3) {
            fy  = flow[(size_t)(n * 2 + 1) * 16384 + y * 128 + x];
            fx2 = flow[(size_t)(n * 2 + 0) * 16384 + y * 128 + x];
        }
        #pragma unroll
        for (int m = 0; m < 4; ++m) {
            int o0 = m * 16 + q * 4;
            f32x4 v = acc[m][p];
            if (MODE == 0) {
                *(f32x4*)(partial + pxi * 64 + o0) = v;
            } else if (MODE == 1 || MODE == 2) {
                f32x4 bv = *(const f32x4*)(bias + o0);
                if (MODE == 1) {
                    f32x4 pv = *(const f32x4*)(partial + pxi * 64 + o0);
                    v += pv;
                }
                v += bv;
                s16x4 r;
                #pragma unroll
                for (int j = 0; j < 4; ++j) {
                    float t = v[j];
                    t = t >= 0.f ? t : 0.1f * t;
                    r[j] = f2bf(t);
                }
                *(s16x4*)(outB + pxi * 64 + o0) = r;
            } else {  // MODE 3: g-planar offset+mask planes (x-coalesced)
                int oc4 = og * 64 + o0;
                if (oc4 < 432) {
                    f32x4 bv = *(const f32x4*)(bias + oc4);
                    v += bv;
                    size_t nrel = (size_t)(bid >> 7);
                    int pxl = y * 128 + x;
                    if (oc4 < 288) {
                        int gk0 = oc4 >> 1;
                        int g0 = gk0 / 9, t0 = gk0 - g0 * 9;
                        int gk1 = gk0 + 1;
                        int g1 = gk1 / 9, t1 = gk1 - g1 * 9;
                        unsigned pk0 = (unsigned)(unsigned short)f2h(v[0] + fy) |
                                       ((unsigned)(unsigned short)f2h(v[1] + fx2) << 16);
                        unsigned pk1 = (unsigned)(unsigned short)f2h(v[2] + fy) |
                                       ((unsigned)(unsigned short)f2h(v[3] + fx2) << 16);
                        offP[((nrel * 9 + t0) * 16 + g0) * 16384 + (size_t)pxl] = (int)pk0;
                        offP[((nrel * 9 + t1) * 16 + g1) * 16384 + (size_t)pxl] = (int)pk1;
                    } else {
                        int gkb = oc4 - 288;
                        #pragma unroll
                        for (int j = 0; j < 4; ++j) {
                            int gk = gkb + j;
                            int g = gk / 9, t = gk - g * 9;
                            maskP[((nrel * 9 + t) * 16 + g) * 16384 + (size_t)pxl] =
                                f2h(1.f / (1.f + expf(-v[j])));
                        }
                    }
                }
            }
        }
    }
}

// ---------------------------------------------------------------------------
// DCN: block = 64-pixel row strip, 4 waves (R22-proven) + XCD-aware block
// swizzle: each XCD gets 128 consecutive strips -> nbrG working set ~1MB
// fits its private L2 (was: whole 16.8MB footprint per XCD).
// ---------------------------------------------------------------------------
__global__ __launch_bounds__(256) void k_dcn(
    const int* __restrict__ offP, const short* __restrict__ maskP,
    const short* __restrict__ nbrG, const short* __restrict__ dcwT,
    const float* __restrict__ dcb, float* __restrict__ out, int n0)
{
    __shared__ __align__(16) short smp[64 * 64];  // [px][ic], 16B-chunk XOR swizzle
    __shared__ __align__(16) short aS[64 * 64];

    int tid = threadIdx.x;
    int bid0 = blockIdx.x;           // 1024 blocks (4 img * 256 strips)
    int bid = (bid0 & 7) * 128 + (bid0 >> 3);  // XCD-contiguous remap (bijective)
    int nrel = bid >> 8;
    int rb = bid & 255;
    int y = rb >> 1;
    int xh = (rb & 1) << 6;
    int n = n0 + nrel;

    int xt = tid & 63;               // x within strip (sample phase)
    int sg = tid >> 6;               // wave id = g-group
    int ln = tid & 63, c = ln & 15, q = ln >> 4;
    int x = xh + xt;
    int pxl = y * 128 + x;

    int aoc = tid >> 3, ac8 = tid & 7;
    i32x4 sa0 = *(const i32x4*)(dcwT + (size_t)aoc * 576 + ac8 * 8);
    i32x4 sa1 = *(const i32x4*)(dcwT + (size_t)(aoc + 32) * 576 + ac8 * 8);

    const short* plg0 = nbrG + (size_t)(n * 16 + sg * 4) * 65536;

    f32x4 acc[4];
    #pragma unroll
    for (int m = 0; m < 4; ++m) acc[m] = (f32x4){0.f, 0.f, 0.f, 0.f};

    int brow = sg * 16 + c;          // wave's output pixel row in smp

    for (int tap = 0; tap < 9; ++tap) {
        int dty = tap / 3 - 1, dtx = tap - (tap / 3) * 3 - 1;
        size_t pbase = ((size_t)(nrel * 9 + tap) * 16 + sg * 4) * 16384 + pxl;
        i32x4 dd4;
        s16x4 mk4;
        #pragma unroll
        for (int gg = 0; gg < 4; ++gg) {
            dd4[gg] = offP[pbase + (size_t)gg * 16384];
            mk4[gg] = maskP[pbase + (size_t)gg * 16384];
        }

        s16x8 r01[2];
        #pragma unroll
        for (int gg = 0; gg < 4; ++gg) {
            float dyv = h2f((short)(dd4[gg] & 0xffff));
            float dxv = h2f((short)(((unsigned)dd4[gg]) >> 16));
            float mk  = h2f(mk4[gg]);
            float sy = (float)(y + dty) + dyv;
            float sx = (float)(x + dtx) + dxv;
            float y0f = floorf(sy), x0f = floorf(sx);
            int y0 = (int)y0f, x0 = (int)x0f;
            float ddy = sy - y0f, ddx = sx - x0f;
            float vy0 = ((unsigned)y0 < 128u) ? 1.f : 0.f;
            float vy1 = ((unsigned)(y0 + 1) < 128u) ? 1.f : 0.f;
            float vx0 = ((unsigned)x0 < 128u) ? 1.f : 0.f;
            float vx1 = ((unsigned)(x0 + 1) < 128u) ? 1.f : 0.f;
            float w00 = (1.f - ddy) * (1.f - ddx) * vy0 * vx0;
            float w01 = (1.f - ddy) * ddx * vy0 * vx1;
            float w10 = ddy * (1.f - ddx) * vy1 * vx0;
            float w11 = ddy * ddx * vy1 * vx1;
            int y0c = min(max(y0, 0), 127), y1c = min(max(y0 + 1, 0), 127);
            int x0c = min(max(x0, 0), 127), x1c = min(max(x0 + 1, 0), 127);
            int xb = min(max(x0, 0), 126);
            bool sel0 = (x0c == xb), sel1 = (x1c == xb);
            const short* plg = plg0 + (size_t)gg * 65536;
            s16x8 pr0 = *(const s16x8*)(plg + (y0c * 128 + xb) * 4);
            s16x8 pr1 = *(const s16x8*)(plg + (y1c * 128 + xb) * 4);
            #pragma unroll
            for (int cc = 0; cc < 4; ++cc) {
                float v00 = b2f(sel0 ? pr0[cc] : pr0[4 + cc]);
                float v01 = b2f(sel1 ? pr0[cc] : pr0[4 + cc]);
                float v10 = b2f(sel0 ? pr1[cc] : pr1[4 + cc]);
                float v11 = b2f(sel1 ? pr1[cc] : pr1[4 + cc]);
                float sv = w00 * v00 + w01 * v01 + w10 * v10 + w11 * v11;
                r01[gg >> 1][(gg & 1) * 4 + cc] = f2bf(sv * mk);
            }
        }
        // write samples: row xt, chunks sg*2, sg*2+1 (XOR swizzle)
        *(s16x8*)((char*)smp + xt * 128 + (((sg * 2 + 0) ^ (xt & 7)) << 4)) = r01[0];
        *(s16x8*)((char*)smp + xt * 128 + (((sg * 2 + 1) ^ (xt & 7)) << 4)) = r01[1];
        // stage A (conv-proven pattern) + prefetch next tap
        *(i32x4*)((char*)aS + aoc * 128 + ((ac8 ^ (aoc & 7)) << 4)) = sa0;
        *(i32x4*)((char*)aS + (aoc + 32) * 128 + ((ac8 ^ ((aoc + 32) & 7)) << 4)) = sa1;
        if (tap < 8) {
            sa0 = *(const i32x4*)(dcwT + (size_t)aoc * 576 + (tap + 1) * 64 + ac8 * 8);
            sa1 = *(const i32x4*)(dcwT + (size_t)(aoc + 32) * 576 + (tap + 1) * 64 + ac8 * 8);
        }
        __syncthreads();  // smp + aS ready

        #pragma unroll
        for (int ih = 0; ih < 2; ++ih) {
            int slot = ih * 4 + q;
            s16x8 bf = *(const s16x8*)((const char*)smp + brow * 128 + ((slot ^ (brow & 7)) << 4));
            #pragma unroll
            for (int m = 0; m < 4; ++m) {
                int ocl = m * 16 + c;
                s16x8 a = *(const s16x8*)((const char*)aS + ocl * 128 + ((slot ^ (ocl & 7)) << 4));
                acc[m] = __builtin_amdgcn_mfma_f32_16x16x32_bf16(a, bf, acc[m], 0, 0, 0);
            }
        }
        __syncthreads();  // done reading smp/aS
    }

    #pragma unroll
    for (int m = 0; m < 4; ++m) {
        int o0 = m * 16 + q * 4;
        f32x4 bv = *(const f32x4*)(dcb + o0);
        f32x4 v = acc[m] + bv;
        int xo = xh + sg * 16 + c;
        #pragma unroll
        for (int j = 0; j < 4; ++j) {
            float t = v[j];
            t = t >= 0.f ? t : 0.1f * t;
            out[((size_t)n * 64 + o0 + j) * 16384 + y * 128 + xo] = t;
        }
    }
}

// ---------------------------------------------------------------------------
extern "C" void kernel_launch(void* const* d_in, const int* in_sizes, int n_in,
                              void* d_out, int out_size, void* d_ws, size_t ws_size,
                              hipStream_t stream)
{
    const float* nbr  = (const float*)d_in[0];
    const float* ref  = (const float*)d_in[1];
    const float* flow = (const float*)d_in[2];
    const float* w1   = (const float*)d_in[3];
    const float* b1   = (const float*)d_in[4];
    const float* w2   = (const float*)d_in[5];
    const float* b2   = (const float*)d_in[6];
    const float* w3   = (const float*)d_in[7];
    const float* b3   = (const float*)d_in[8];
    const float* w4   = (const float*)d_in[9];
    const float* b4   = (const float*)d_in[10];
    const float* dcw  = (const float*)d_in[11];
    const float* dcb  = (const float*)d_in[12];
    float* out = (float*)d_out;
    char* ws = (char*)d_ws;

    // ws layout (bytes), peak 91.23 MB (proven rounds 6/8/13/14/18/21/22).
    short* nbrG   = (short*)ws;
    short* wpool  = (short*)(ws + 16777216);
    short* warped = (short*)(ws + 17825792);
    short* refH   = (short*)(ws + 34603008);
    float* h1p    = (float*)(ws + 51380224);
    int*   offP   = (int*)(ws + 17825792);
    short* maskP  = (short*)(ws + 55574528);
    short* h3     = (short*)(ws + 74448896);
    short* h1     = warped;
    short* h2     = refH;

    short* wT1a = wpool;            // w1 ic 0-63
    short* wT1b = wpool + 36864;    // w1 ic 64-127
    short* wT2  = wpool + 73728;
    short* wT3  = wpool + 110592;
    short* wT4  = wpool + 147456;   // [448][9][64]
    short* dcwT = wpool + 405504;

    k_wt_all<<<1728, 256, 0, stream>>>(w1, w2, w3, w4, dcw, wpool);
    k_nhwc2<<<1024, 256, 0, stream>>>(nbr, ref, nbrG, refH);
    k_backwarp<<<2048, 256, 0, stream>>>(nbrG, flow, warped);

    // conv1 as two IC-64 passes
    k_conv<0><<<1024, 256, 0, stream>>>(warped, wT1a, nullptr, h1p, nullptr, nullptr, nullptr, nullptr, 0);
    k_conv<1><<<1024, 256, 0, stream>>>(refH, wT1b, b1, h1p, h1, nullptr, nullptr, nullptr, 0);
    k_conv<2><<<1024, 256, 0, stream>>>(h1, wT2, b2, nullptr, h2, nullptr, nullptr, nullptr, 0);
    k_conv<2><<<1024, 256, 0, stream>>>(h2, wT3, b3, nullptr, h3, nullptr, nullptr, nullptr, 0);

    // conv4 + DCN in 4-image chunks
    for (int n0 = 0; n0 < 8; n0 += 4) {
        dim3 g4(512, 7);
        k_conv<3><<<g4, 256, 0, stream>>>(h3, wT4, b4, nullptr, nullptr, offP, maskP, flow, n0);
        k_dcn<<<1024, 256, 0, stream>>>(offP, maskP, nbrG, dcwT, dcb, out, n0);
    }
}

// Round 24
// 299.671 us; speedup vs baseline: 1.1920x; 1.0107x over previous
//
#include <hip/hip_runtime.h>
#include <math.h>

#define H 128
#define W 128
#define NB 8
#define NFC 64

typedef __attribute__((ext_vector_type(8))) short s16x8;
typedef __attribute__((ext_vector_type(4))) short s16x4;
typedef __attribute__((ext_vector_type(4))) float f32x4;
typedef __attribute__((ext_vector_type(4))) int   i32x4;
typedef __attribute__((ext_vector_type(2))) int   i32x2;

__device__ __forceinline__ float b2f(short s) {
    return __uint_as_float(((unsigned)(unsigned short)s) << 16);
}
__device__ __forceinline__ short f2bf(float f) {
    unsigned u = __float_as_uint(f);
    u += 0x7FFF + ((u >> 16) & 1);
    return (short)(u >> 16);
}
__device__ __forceinline__ short f2h(float f) {
    _Float16 h = (_Float16)f;
    return __builtin_bit_cast(short, h);
}
__device__ __forceinline__ float h2f(short s) {
    return (float)__builtin_bit_cast(_Float16, s);
}

// ---------------------------------------------------------------------------
// all weight transforms in one launch -> wpool bf16 [768][9][64]
// ---------------------------------------------------------------------------
__global__ __launch_bounds__(256) void k_wt_all(
    const float* __restrict__ w1, const float* __restrict__ w2,
    const float* __restrict__ w3, const float* __restrict__ w4,
    const float* __restrict__ dcw, short* __restrict__ wp)
{
    int idx = blockIdx.x * 256 + threadIdx.x;   // < 442368
    int u = idx / 576;
    int r = idx - u * 576;
    int t = r >> 6, i = r & 63;
    float v;
    if (u < 128) {
        int o = u & 63, icoff = (u >> 6) << 6;
        v = w1[((size_t)(o * 128) + icoff + i) * 9 + t];
    } else if (u < 192) {
        int o = u - 128;
        v = w2[((size_t)(o * 64) + i) * 9 + t];
    } else if (u < 256) {
        int o = u - 192;
        v = w3[((size_t)(o * 64) + i) * 9 + t];
    } else if (u < 704) {
        int o = u - 256;
        v = (o < 432) ? w4[((size_t)(o * 64) + i) * 9 + t] : 0.f;
    } else {
        int o = u - 704;
        v = dcw[((size_t)(o * 64) + i) * 9 + t];
    }
    wp[idx] = f2bf(v);
}

// ---------------------------------------------------------------------------
// NCHW fp32 -> (nbr: g-planar bf16 [n][16][128][128][4]) and (ref: NHWC bf16)
// ---------------------------------------------------------------------------
__global__ __launch_bounds__(256) void k_nhwc2(const float* __restrict__ nbr,
                                               const float* __restrict__ ref,
                                               short* __restrict__ nbrG,
                                               short* __restrict__ refH)
{
    int px = blockIdx.x * 256 + threadIdx.x;
    bool isNbr = (px < 131072);
    const float* src;
    if (isNbr) { src = nbr; }
    else       { src = ref; px -= 131072; }
    int n = px >> 14;
    int sp = px & 16383;
    const float* s = src + (size_t)n * 64 * 16384 + sp;
    unsigned pk[32];
    #pragma unroll
    for (int c = 0; c < 32; ++c) {
        float v0 = s[(size_t)(2 * c) * 16384];
        float v1 = s[(size_t)(2 * c + 1) * 16384];
        pk[c] = (unsigned)(unsigned short)f2bf(v0) |
                ((unsigned)(unsigned short)f2bf(v1) << 16);
    }
    if (isNbr) {
        #pragma unroll
        for (int g = 0; g < 16; ++g) {
            i32x2 t;
            t[0] = pk[2 * g]; t[1] = pk[2 * g + 1];
            *(i32x2*)(nbrG + ((size_t)(n * 16 + g) * 16384 + sp) * 4) = t;
        }
    } else {
        i32x4* d = (i32x4*)(refH + (size_t)(n * 16384 + sp) * 64);
        #pragma unroll
        for (int qq = 0; qq < 8; ++qq) {
            i32x4 t;
            t[0] = pk[4 * qq]; t[1] = pk[4 * qq + 1];
            t[2] = pk[4 * qq + 2]; t[3] = pk[4 * qq + 3];
            d[qq] = t;
        }
    }
}

// ---------------------------------------------------------------------------
// backwarp: nbrG (g-planar bf16) + flow -> warped (NHWC bf16)
// ---------------------------------------------------------------------------
__global__ __launch_bounds__(256) void k_backwarp(const short* __restrict__ nbrG,
                                                  const float* __restrict__ flow,
                                                  short* __restrict__ warped)
{
    int idx = blockIdx.x * 256 + threadIdx.x;
    int px = idx >> 2, qt = idx & 3;
    int n = px >> 14;
    int x = px & 127, y = (px >> 7) & 127;
    float fx = flow[(size_t)(n * 2 + 0) * 16384 + y * 128 + x];
    float fy = flow[(size_t)(n * 2 + 1) * 16384 + y * 128 + x];
    float pxf = (float)x + fx, pyf = (float)y + fy;
    float x0f = floorf(pxf), y0f = floorf(pyf);
    int x0 = (int)x0f, y0 = (int)y0f;
    float dx = pxf - x0f, dy = pyf - y0f;
    float vy0 = ((unsigned)y0 < 128u) ? 1.f : 0.f;
    float vy1 = ((unsigned)(y0 + 1) < 128u) ? 1.f : 0.f;
    float vx0 = ((unsigned)x0 < 128u) ? 1.f : 0.f;
    float vx1 = ((unsigned)(x0 + 1) < 128u) ? 1.f : 0.f;
    float w00 = (1.f - dy) * (1.f - dx) * vy0 * vx0;
    float w01 = (1.f - dy) * dx * vy0 * vx1;
    float w10 = dy * (1.f - dx) * vy1 * vx0;
    float w11 = dy * dx * vy1 * vx1;
    int y0c = min(max(y0, 0), 127), y1c = min(max(y0 + 1, 0), 127);
    int x0c = min(max(x0, 0), 127), x1c = min(max(x0 + 1, 0), 127);
    int xb = min(max(x0, 0), 126);
    bool s0 = (x0c == xb), s1 = (x1c == xb);

    const short* plbase = nbrG + (size_t)n * 16 * 65536;
    s16x8 r0, r1;
    #pragma unroll
    for (int pg = 0; pg < 4; ++pg) {
        const short* pl = plbase + (size_t)(qt * 4 + pg) * 65536;
        s16x8 p0 = *(const s16x8*)(pl + (y0c * 128 + xb) * 4);
        s16x8 p1 = *(const s16x8*)(pl + (y1c * 128 + xb) * 4);
        #pragma unroll
        for (int cc = 0; cc < 4; ++cc) {
            float v00 = b2f(s0 ? p0[cc] : p0[4 + cc]);
            float v01 = b2f(s1 ? p0[cc] : p0[4 + cc]);
            float v10 = b2f(s0 ? p1[cc] : p1[4 + cc]);
            float v11 = b2f(s1 ? p1[cc] : p1[4 + cc]);
            float v = w00 * v00 + w01 * v01 + w10 * v10 + w11 * v11;
            short res = f2bf(v);
            if (pg < 2) r0[pg * 4 + cc] = res;
            else        r1[(pg - 2) * 4 + cc] = res;
        }
    }
    short* o = warped + (size_t)px * 64 + qt * 16;
    *(s16x8*)o = r0;
    *(s16x8*)(o + 8) = r1;
}

// ---------------------------------------------------------------------------
// MFMA conv3x3, IC=64 (dbuf aS, 1 barrier/tap, row-strip patches; R22-proven).
// XCD-aware swizzle:
//   MODE 0-2: bid = (b&7)*128 + b>>3  (each XCD: 128 contiguous tiles)
//   MODE 3:   cid=(y*512+x); xcd=cid&7; slot=cid>>3; og=slot%7;
//             tile = xcd*64 + slot/7  (each XCD: 64 tiles x all 7 og,
//             og fastest -> h3 tile halo L2-resident across og re-reads)
// MODE 3 epilogue writes G-PLANAR offset+mask planes.
// ---------------------------------------------------------------------------
template<int MODE>
__global__ __launch_bounds__(256) void k_conv(
    const short* __restrict__ in, const short* __restrict__ wT,
    const float* __restrict__ bias,
    float* __restrict__ partial, short* __restrict__ outB,
    int* __restrict__ offP, short* __restrict__ maskP,
    const float* __restrict__ flow, int n0)
{
    __shared__ __align__(16) short tileS[180 * 64];
    __shared__ __align__(16) short aS[2][64 * 64];

    int tid = threadIdx.x;
    int og, n, tl, nrel;
    if (MODE == 3) {
        int cid = (int)blockIdx.y * 512 + (int)blockIdx.x;  // 0..3583
        int slot = cid >> 3;           // 0..447
        og = slot % 7;
        int tla = (cid & 7) * 64 + slot / 7;  // 0..511
        nrel = tla >> 7;
        n = n0 + nrel;
        tl = tla & 127;
    } else {
        int bid0 = (int)blockIdx.x;
        int bids = (bid0 & 7) * 128 + (bid0 >> 3);
        og = 0; nrel = 0;
        n = bids >> 7;
        tl = bids & 127;
    }
    int bx = (tl & 7) << 4;
    int by = (tl >> 3) << 3;
    int ln = tid & 63, wv = tid >> 6;
    int c = ln & 15, q = ln >> 4;

    for (int i = tid; i < 1440; i += 256) {
        int pt = i >> 3, c16 = i & 7;
        int ty = pt / 18, tx = pt - ty * 18;
        int gy = by + ty - 1, gx = bx + tx - 1;
        i32x4 v = {0, 0, 0, 0};
        if ((unsigned)gy < 128u && (unsigned)gx < 128u)
            v = *(const i32x4*)(in + (((size_t)n * 128 + gy) * 128 + gx) * 64 + c16 * 8);
        *(i32x4*)((char*)tileS + pt * 128 + ((c16 ^ (pt & 7)) << 4)) = v;
    }

    const short* wbase = wT + ((MODE == 3) ? (size_t)og * 36864 : 0);
    int aoc = tid >> 3, ac8 = tid & 7;
    {
        i32x4 t0a = *(const i32x4*)(wbase + (size_t)aoc * 576 + ac8 * 8);
        i32x4 t0b = *(const i32x4*)(wbase + (size_t)(aoc + 32) * 576 + ac8 * 8);
        *(i32x4*)((char*)aS[0] + aoc * 128 + ((ac8 ^ (aoc & 7)) << 4)) = t0a;
        *(i32x4*)((char*)aS[0] + (aoc + 32) * 128 + ((ac8 ^ ((aoc + 32) & 7)) << 4)) = t0b;
    }
    i32x4 sa0 = *(const i32x4*)(wbase + (size_t)aoc * 576 + 64 + ac8 * 8);
    i32x4 sa1 = *(const i32x4*)(wbase + (size_t)(aoc + 32) * 576 + 64 + ac8 * 8);

    f32x4 acc[4][2];
    #pragma unroll
    for (int m = 0; m < 4; ++m) {
        acc[m][0] = (f32x4){0.f, 0.f, 0.f, 0.f};
        acc[m][1] = (f32x4){0.f, 0.f, 0.f, 0.f};
    }

    int row0 = 2 * wv, row1 = 2 * wv + 1;   // wave's two row-strip patches

    __syncthreads();  // tile + aS[0] ready

    for (int tap = 0; tap < 9; ++tap) {
        int cur = tap & 1;
        if (tap < 8) {
            *(i32x4*)((char*)aS[cur ^ 1] + aoc * 128 + ((ac8 ^ (aoc & 7)) << 4)) = sa0;
            *(i32x4*)((char*)aS[cur ^ 1] + (aoc + 32) * 128 + ((ac8 ^ ((aoc + 32) & 7)) << 4)) = sa1;
            if (tap < 7) {
                sa0 = *(const i32x4*)(wbase + (size_t)aoc * 576 + (tap + 2) * 64 + ac8 * 8);
                sa1 = *(const i32x4*)(wbase + (size_t)(aoc + 32) * 576 + (tap + 2) * 64 + ac8 * 8);
            }
        }

        int dty = tap / 3, dtx = tap - dty * 3;
        int pta = (row0 + dty) * 18 + c + dtx;
        int ptb = (row1 + dty) * 18 + c + dtx;
        #pragma unroll
        for (int ih = 0; ih < 2; ++ih) {
            int slot = ih * 4 + q;
            s16x8 bf0 = *(const s16x8*)((const char*)tileS + pta * 128 + ((slot ^ (pta & 7)) << 4));
            s16x8 bf1 = *(const s16x8*)((const char*)tileS + ptb * 128 + ((slot ^ (ptb & 7)) << 4));
            #pragma unroll
            for (int m = 0; m < 4; ++m) {
                int ocl = m * 16 + c;
                s16x8 a = *(const s16x8*)((const char*)aS[cur] + ocl * 128 + ((slot ^ (ocl & 7)) << 4));
                acc[m][0] = __builtin_amdgcn_mfma_f32_16x16x32_bf16(a, bf0, acc[m][0], 0, 0, 0);
                acc[m][1] = __builtin_amdgcn_mfma_f32_16x16x32_bf16(a, bf1, acc[m][1], 0, 0, 0);
            }
        }
        if (tap < 8) __syncthreads();
    }

    #pragma unroll
    for (int p = 0; p < 2; ++p) {
        int y = by + (p ? row1 : row0);
        int x = bx + c;
        size_t pxi = ((size_t)n * 128 + y) * 128 + x;
        float fy = 0.f, fx2 = 0.f;
        if (MODE == 3) {
            fy  = flow[(size_t)(n * 2 + 1) * 16384 + y * 128 + x];
            fx2 = flow[(size_t)(n * 2 + 0) * 16384 + y * 128 + x];
        }
        #pragma unroll
        for (int m = 0; m < 4; ++m) {
            int o0 = m * 16 + q * 4;
            f32x4 v = acc[m][p];
            if (MODE == 0) {
                *(f32x4*)(partial + pxi * 64 + o0) = v;
            } else if (MODE == 1 || MODE == 2) {
                f32x4 bv = *(const f32x4*)(bias + o0);
                if (MODE == 1) {
                    f32x4 pv = *(const f32x4*)(partial + pxi * 64 + o0);
                    v += pv;
                }
                v += bv;
                s16x4 r;
                #pragma unroll
                for (int j = 0; j < 4; ++j) {
                    float t = v[j];
                    t = t >= 0.f ? t : 0.1f * t;
                    r[j] = f2bf(t);
                }
                *(s16x4*)(outB + pxi * 64 + o0) = r;
            } else {  // MODE 3: g-planar offset+mask planes (x-coalesced)
                int oc4 = og * 64 + o0;
                if (oc4 < 432) {
                    f32x4 bv = *(const f32x4*)(bias + oc4);
                    v += bv;
                    int pxl = y * 128 + x;
                    if (oc4 < 288) {
                        int gk0 = oc4 >> 1;
                        int g0 = gk0 / 9, t0 = gk0 - g0 * 9;
                        int gk1 = gk0 + 1;
                        int g1 = gk1 / 9, t1 = gk1 - g1 * 9;
                        unsigned pk0 = (unsigned)(unsigned short)f2h(v[0] + fy) |
                                       ((unsigned)(unsigned short)f2h(v[1] + fx2) << 16);
                        unsigned pk1 = (unsigned)(unsigned short)f2h(v[2] + fy) |
                                       ((unsigned)(unsigned short)f2h(v[3] + fx2) << 16);
                        offP[((nrel * 9 + t0) * 16 + g0) * 16384 + (size_t)pxl] = (int)pk0;
                        offP[((nrel * 9 + t1) * 16 + g1) * 16384 + (size_t)pxl] = (int)pk1;
                    } else {
                        int gkb = oc4 - 288;
                        #pragma unroll
                        for (int j = 0; j < 4; ++j) {
                            int gk = gkb + j;
                            int g = gk / 9, t = gk - g * 9;
                            maskP[((nrel * 9 + t) * 16 + g) * 16384 + (size_t)pxl] =
                                f2h(1.f / (1.f + expf(-v[j])));
                        }
                    }
                }
            }
        }
    }
}

// ---------------------------------------------------------------------------
// DCN: block = 64-pixel row strip, 4 waves + XCD swizzle (R23-proven).
// ---------------------------------------------------------------------------
__global__ __launch_bounds__(256) void k_dcn(
    const int* __restrict__ offP, const short* __restrict__ maskP,
    const short* __restrict__ nbrG, const short* __restrict__ dcwT,
    const float* __restrict__ dcb, float* __restrict__ out, int n0)
{
    __shared__ __align__(16) short smp[64 * 64];  // [px][ic], 16B-chunk XOR swizzle
    __shared__ __align__(16) short aS[64 * 64];

    int tid = threadIdx.x;
    int bid0 = blockIdx.x;           // 1024 blocks (4 img * 256 strips)
    int bid = (bid0 & 7) * 128 + (bid0 >> 3);  // XCD-contiguous remap (bijective)
    int nrel = bid >> 8;
    int rb = bid & 255;
    int y = rb >> 1;
    int xh = (rb & 1) << 6;
    int n = n0 + nrel;

    int xt = tid & 63;               // x within strip (sample phase)
    int sg = tid >> 6;               // wave id = g-group
    int ln = tid & 63, c = ln & 15, q = ln >> 4;
    int x = xh + xt;
    int pxl = y * 128 + x;

    int aoc = tid >> 3, ac8 = tid & 7;
    i32x4 sa0 = *(const i32x4*)(dcwT + (size_t)aoc * 576 + ac8 * 8);
    i32x4 sa1 = *(const i32x4*)(dcwT + (size_t)(aoc + 32) * 576 + ac8 * 8);

    const short* plg0 = nbrG + (size_t)(n * 16 + sg * 4) * 65536;

    f32x4 acc[4];
    #pragma unroll
    for (int m = 0; m < 4; ++m) acc[m] = (f32x4){0.f, 0.f, 0.f, 0.f};

    int brow = sg * 16 + c;          // wave's output pixel row in smp

    for (int tap = 0; tap < 9; ++tap) {
        int dty = tap / 3 - 1, dtx = tap - (tap / 3) * 3 - 1;
        size_t pbase = ((size_t)(nrel * 9 + tap) * 16 + sg * 4) * 16384 + pxl;
        i32x4 dd4;
        s16x4 mk4;
        #pragma unroll
        for (int gg = 0; gg < 4; ++gg) {
            dd4[gg] = offP[pbase + (size_t)gg * 16384];
            mk4[gg] = maskP[pbase + (size_t)gg * 16384];
        }

        s16x8 r01[2];
        #pragma unroll
        for (int gg = 0; gg < 4; ++gg) {
            float dyv = h2f((short)(dd4[gg] & 0xffff));
            float dxv = h2f((short)(((unsigned)dd4[gg]) >> 16));
            float mk  = h2f(mk4[gg]);
            float sy = (float)(y + dty) + dyv;
            float sx = (float)(x + dtx) + dxv;
            float y0f = floorf(sy), x0f = floorf(sx);
            int y0 = (int)y0f, x0 = (int)x0f;
            float ddy = sy - y0f, ddx = sx - x0f;
            float vy0 = ((unsigned)y0 < 128u) ? 1.f : 0.f;
            float vy1 = ((unsigned)(y0 + 1) < 128u) ? 1.f : 0.f;
            float vx0 = ((unsigned)x0 < 128u) ? 1.f : 0.f;
            float vx1 = ((unsigned)(x0 + 1) < 128u) ? 1.f : 0.f;
            float w00 = (1.f - ddy) * (1.f - ddx) * vy0 * vx0;
            float w01 = (1.f - ddy) * ddx * vy0 * vx1;
            float w10 = ddy * (1.f - ddx) * vy1 * vx0;
            float w11 = ddy * ddx * vy1 * vx1;
            int y0c = min(max(y0, 0), 127), y1c = min(max(y0 + 1, 0), 127);
            int x0c = min(max(x0, 0), 127), x1c = min(max(x0 + 1, 0), 127);
            int xb = min(max(x0, 0), 126);
            bool sel0 = (x0c == xb), sel1 = (x1c == xb);
            const short* plg = plg0 + (size_t)gg * 65536;
            s16x8 pr0 = *(const s16x8*)(plg + (y0c * 128 + xb) * 4);
            s16x8 pr1 = *(const s16x8*)(plg + (y1c * 128 + xb) * 4);
            #pragma unroll
            for (int cc = 0; cc < 4; ++cc) {
                float v00 = b2f(sel0 ? pr0[cc] : pr0[4 + cc]);
                float v01 = b2f(sel1 ? pr0[cc] : pr0[4 + cc]);
                float v10 = b2f(sel0 ? pr1[cc] : pr1[4 + cc]);
                float v11 = b2f(sel1 ? pr1[cc] : pr1[4 + cc]);
                float sv = w00 * v00 + w01 * v01 + w10 * v10 + w11 * v11;
                r01[gg >> 1][(gg & 1) * 4 + cc] = f2bf(sv * mk);
            }
        }
        // write samples: row xt, chunks sg*2, sg*2+1 (XOR swizzle)
        *(s16x8*)((char*)smp + xt * 128 + (((sg * 2 + 0) ^ (xt & 7)) << 4)) = r01[0];
        *(s16x8*)((char*)smp + xt * 128 + (((sg * 2 + 1) ^ (xt & 7)) << 4)) = r01[1];
        // stage A (conv-proven pattern) + prefetch next tap
        *(i32x4*)((char*)aS + aoc * 128 + ((ac8 ^ (aoc & 7)) << 4)) = sa0;
        *(i32x4*)((char*)aS + (aoc + 32) * 128 + ((ac8 ^ ((aoc + 32) & 7)) << 4)) = sa1;
        if (tap < 8) {
            sa0 = *(const i32x4*)(dcwT + (size_t)aoc * 576 + (tap + 1) * 64 + ac8 * 8);
            sa1 = *(const i32x4*)(dcwT + (size_t)(aoc + 32) * 576 + (tap + 1) * 64 + ac8 * 8);
        }
        __syncthreads();  // smp + aS ready

        #pragma unroll
        for (int ih = 0; ih < 2; ++ih) {
            int slot = ih * 4 + q;
            s16x8 bf = *(const s16x8*)((const char*)smp + brow * 128 + ((slot ^ (brow & 7)) << 4));
            #pragma unroll
            for (int m = 0; m < 4; ++m) {
                int ocl = m * 16 + c;
                s16x8 a = *(const s16x8*)((const char*)aS + ocl * 128 + ((slot ^ (ocl & 7)) << 4));
                acc[m] = __builtin_amdgcn_mfma_f32_16x16x32_bf16(a, bf, acc[m], 0, 0, 0);
            }
        }
        __syncthreads();  // done reading smp/aS
    }

    #pragma unroll
    for (int m = 0; m < 4; ++m) {
        int o0 = m * 16 + q * 4;
        f32x4 bv = *(const f32x4*)(dcb + o0);
        f32x4 v = acc[m] + bv;
        int xo = xh + sg * 16 + c;
        #pragma unroll
        for (int j = 0; j < 4; ++j) {
            float t = v[j];
            t = t >= 0.f ? t : 0.1f * t;
            out[((size_t)n * 64 + o0 + j) * 16384 + y * 128 + xo] = t;
        }
    }
}

// ---------------------------------------------------------------------------
extern "C" void kernel_launch(void* const* d_in, const int* in_sizes, int n_in,
                              void* d_out, int out_size, void* d_ws, size_t ws_size,
                              hipStream_t stream)
{
    const float* nbr  = (const float*)d_in[0];
    const float* ref  = (const float*)d_in[1];
    const float* flow = (const float*)d_in[2];
    const float* w1   = (const float*)d_in[3];
    const float* b1   = (const float*)d_in[4];
    const float* w2   = (const float*)d_in[5];
    const float* b2   = (const float*)d_in[6];
    const float* w3   = (const float*)d_in[7];
    const float* b3   = (const float*)d_in[8];
    const float* w4   = (const float*)d_in[9];
    const float* b4   = (const float*)d_in[10];
    const float* dcw  = (const float*)d_in[11];
    const float* dcb  = (const float*)d_in[12];
    float* out = (float*)d_out;
    char* ws = (char*)d_ws;

    // ws layout (bytes), peak 91.23 MB (proven rounds 6/8/13/14/18/21/22/23).
    short* nbrG   = (short*)ws;
    short* wpool  = (short*)(ws + 16777216);
    short* warped = (short*)(ws + 17825792);
    short* refH   = (short*)(ws + 34603008);
    float* h1p    = (float*)(ws + 51380224);
    int*   offP   = (int*)(ws + 17825792);
    short* maskP  = (short*)(ws + 55574528);
    short* h3     = (short*)(ws + 74448896);
    short* h1     = warped;
    short* h2     = refH;

    short* wT1a = wpool;            // w1 ic 0-63
    short* wT1b = wpool + 36864;    // w1 ic 64-127
    short* wT2  = wpool + 73728;
    short* wT3  = wpool + 110592;
    short* wT4  = wpool + 147456;   // [448][9][64]
    short* dcwT = wpool + 405504;

    k_wt_all<<<1728, 256, 0, stream>>>(w1, w2, w3, w4, dcw, wpool);
    k_nhwc2<<<1024, 256, 0, stream>>>(nbr, ref, nbrG, refH);
    k_backwarp<<<2048, 256, 0, stream>>>(nbrG, flow, warped);

    // conv1 as two IC-64 passes
    k_conv<0><<<1024, 256, 0, stream>>>(warped, wT1a, nullptr, h1p, nullptr, nullptr, nullptr, nullptr, 0);
    k_conv<1><<<1024, 256, 0, stream>>>(refH, wT1b, b1, h1p, h1, nullptr, nullptr, nullptr, 0);
    k_conv<2><<<1024, 256, 0, stream>>>(h1, wT2, b2, nullptr, h2, nullptr, nullptr, nullptr, 0);
    k_conv<2><<<1024, 256, 0, stream>>>(h2, wT3, b3, nullptr, h3, nullptr, nullptr, nullptr, 0);

    // conv4 + DCN in 4-image chunks
    for (int n0 = 0; n0 < 8; n0 += 4) {
        dim3 g4(512, 7);
        k_conv<3><<<g4, 256, 0, stream>>>(h3, wT4, b4, nullptr, nullptr, offP, maskP, flow, n0);
        k_dcn<<<1024, 256, 0, stream>>>(offP, maskP, nbrG, dcwT, dcb, out, n0);
    }
}